// Round 1
// baseline (325.812 us; speedup 1.0000x reference)
//
#include <hip/hip_runtime.h>
#include <hip/hip_bf16.h>

typedef __bf16 bf16_t;
typedef bf16_t bf16x8 __attribute__((ext_vector_type(8)));
typedef float f32x4 __attribute__((ext_vector_type(4)));
typedef int i32x4 __attribute__((ext_vector_type(4)));

constexpr int C = 256;
constexpr int Bb = 4;
constexpr int N = 4096;   // 64*64 tokens per batch
constexpr int NH = 4;
constexpr int HD = 64;
// fold (1/sqrt(C)) * log2(e) into Q so softmax uses exp2 directly
constexpr float SM_SCALE_LOG2E = 0.0625f * 1.44269504088896340736f;

// byte offset of 16B chunk `chunk` in row `row` of a [rows][64 bf16] LDS tile,
// XOR-swizzled to kill the 128B-row-stride bank conflict (guide G4 / T2)
__device__ __forceinline__ int swz_chunk(int row, int chunk) {
  return row * 128 + ((chunk ^ (row & 7)) << 4);
}

__device__ __forceinline__ f32x4 mfma16(bf16x8 a, bf16x8 b, f32x4 c) {
  return __builtin_amdgcn_mfma_f32_16x16x32_bf16(a, b, c, 0, 0, 0);
}

// ---------------------------------------------------------------------------
// Kernel 1: LayerNorm over C with [B,C,N] -> [B,N,C] transpose, bf16 out
// ---------------------------------------------------------------------------
__global__ __launch_bounds__(256, 2) void ln_kernel(
    const float* __restrict__ x, const float* __restrict__ gamma,
    const float* __restrict__ beta, bf16_t* __restrict__ xn) {
  __shared__ float tile[256][65];       // [channel][token], padded
  __shared__ float red[2][4][64];
  __shared__ float mu_s[64], rs_s[64];
  int tid = threadIdx.x, lane = tid & 63, wv = tid >> 6;
  int b = blockIdx.x >> 6;
  int n0 = (blockIdx.x & 63) << 6;
  const float* xb = x + ((size_t)b * C) * N + n0;
  #pragma unroll 4
  for (int i = 0; i < 64; ++i) {
    int c = wv * 64 + i;
    tile[c][lane] = xb[(size_t)c * N + lane];   // coalesced along tokens
  }
  __syncthreads();
  // token = lane, channel-quarter = wv
  float s = 0.f, s2 = 0.f;
  #pragma unroll 8
  for (int i = 0; i < 64; ++i) {
    float v = tile[wv * 64 + i][lane];
    s += v; s2 += v * v;
  }
  red[0][wv][lane] = s; red[1][wv][lane] = s2;
  __syncthreads();
  if (tid < 64) {
    float ts  = red[0][0][tid] + red[0][1][tid] + red[0][2][tid] + red[0][3][tid];
    float ts2 = red[1][0][tid] + red[1][1][tid] + red[1][2][tid] + red[1][3][tid];
    float mu  = ts * (1.f / 256.f);
    float var = fmaxf(ts2 * (1.f / 256.f) - mu * mu, 0.f);
    mu_s[tid] = mu;
    rs_s[tid] = rsqrtf(var + 1e-5f);
  }
  __syncthreads();
  float g = gamma[tid], be = beta[tid];
  bf16_t* xo = xn + ((size_t)(b * N + n0)) * C + tid;
  #pragma unroll 4
  for (int i = 0; i < 64; ++i) {
    float v = (tile[tid][i] - mu_s[i]) * rs_s[i] * g + be;
    xo[(size_t)i * C] = (bf16_t)v;     // coalesced along channels
  }
}

// ---------------------------------------------------------------------------
// Kernel 2: weights -> bf16, transposed to B^T layout [ncol][k]
// ---------------------------------------------------------------------------
__global__ void conv_w(const float* __restrict__ wqkv, const float* __restrict__ wproj,
                       bf16_t* __restrict__ wqkvT, bf16_t* __restrict__ wprojT) {
  int id = blockIdx.x * 256 + threadIdx.x;
  if (id < 768 * 256) {
    int nn = id >> 8, kk = id & 255;
    wqkvT[id] = (bf16_t)wqkv[(size_t)kk * 768 + nn];
  }
  if (id < 256 * 256) {
    int nn = id >> 8, kk = id & 255;
    wprojT[id] = (bf16_t)wproj[(size_t)kk * 256 + nn];
  }
}

// ---------------------------------------------------------------------------
// Kernel 3: QKV GEMM  xn[16384,256] @ w[256,768] + b  -> Q,K (scaled), Vt
// ---------------------------------------------------------------------------
__global__ __launch_bounds__(256, 4) void gemm_qkv(
    const bf16_t* __restrict__ xn, const bf16_t* __restrict__ wT,
    const float* __restrict__ bias,
    bf16_t* __restrict__ Q, bf16_t* __restrict__ K, bf16_t* __restrict__ Vt) {
  __shared__ char smem[2 * 8192];
  char* As = smem;            // [64 m][64 k] bf16 swizzled
  char* Bs = smem + 8192;     // [64 n][64 k]
  int tid = threadIdx.x, lane = tid & 63, wv = tid >> 6;
  int mt = blockIdx.x & 255, nt = blockIdx.x >> 8;   // 256 x 12
  int m0 = mt * 64, ncol0 = nt * 64;
  f32x4 acc[4];
  #pragma unroll
  for (int i = 0; i < 4; ++i) acc[i] = (f32x4){0.f, 0.f, 0.f, 0.f};
  for (int kt = 0; kt < 4; ++kt) {
    int k0 = kt * 64;
    __syncthreads();
    #pragma unroll
    for (int it = 0; it < 2; ++it) {
      int idx = it * 256 + tid, row = idx >> 3, cb = idx & 7;
      *(i32x4*)(As + swz_chunk(row, cb)) =
          *(const i32x4*)(xn + (size_t)(m0 + row) * C + k0 + cb * 8);
      *(i32x4*)(Bs + swz_chunk(row, cb)) =
          *(const i32x4*)(wT + (size_t)(ncol0 + row) * C + k0 + cb * 8);
    }
    __syncthreads();
    int r = wv * 16 + (lane & 15), q = lane >> 4;
    bf16x8 a0 = *(const bf16x8*)(As + swz_chunk(r, q));
    bf16x8 a1 = *(const bf16x8*)(As + swz_chunk(r, 4 + q));
    #pragma unroll
    for (int ct = 0; ct < 4; ++ct) {
      int br = ct * 16 + (lane & 15);
      bf16x8 b0 = *(const bf16x8*)(Bs + swz_chunk(br, q));
      bf16x8 b1 = *(const bf16x8*)(Bs + swz_chunk(br, 4 + q));
      acc[ct] = mfma16(a0, b0, acc[ct]);
      acc[ct] = mfma16(a1, b1, acc[ct]);
    }
  }
  #pragma unroll
  for (int ct = 0; ct < 4; ++ct) {
    int cg = ncol0 + ct * 16 + (lane & 15);
    float bv = bias[cg];
    int sect = cg >> 8;          // 0=q, 1=k, 2=v
    int cc = cg & 255;
    int h = cc >> 6, d = cc & 63;
    #pragma unroll
    for (int j = 0; j < 4; ++j) {
      int m = m0 + wv * 16 + (lane >> 4) * 4 + j;
      int b_ = m >> 12, n = m & 4095;
      float v = acc[ct][j] + bv;
      if (sect == 0) {
        Q[((size_t)((b_ * NH + h) * N + n)) * HD + d] = (bf16_t)(v * SM_SCALE_LOG2E);
      } else if (sect == 1) {
        K[((size_t)((b_ * NH + h) * N + n)) * HD + d] = (bf16_t)v;
      } else {
        Vt[((size_t)((b_ * NH + h) * HD + d)) * N + n] = (bf16_t)v;  // V transposed
      }
    }
  }
}

// ---------------------------------------------------------------------------
// Kernel 4: flash attention, one 64-row Q tile per block, 4 waves x 16 rows
// ---------------------------------------------------------------------------
__global__ __launch_bounds__(256, 4) void attn_kernel(
    const bf16_t* __restrict__ Q, const bf16_t* __restrict__ K,
    const bf16_t* __restrict__ Vt, bf16_t* __restrict__ aout) {
  __shared__ char smem[3 * 8192];
  char* Kq = smem;             // [64 tok][64 hd]
  char* Vq = smem + 8192;      // [64 hd][64 tok]  (V^T)
  char* Qp = smem + 16384;     // Q tile, then reused per-wave for P
  int tid = threadIdx.x, lane = tid & 63, wv = tid >> 6;
  int bh = blockIdx.x >> 6, qt = blockIdx.x & 63;
  int q0 = qt * 64;
  const bf16_t* Qbase = Q + ((size_t)bh * N + q0) * HD;
  #pragma unroll
  for (int it = 0; it < 2; ++it) {
    int idx = it * 256 + tid, row = idx >> 3, cb = idx & 7;
    *(i32x4*)(Qp + swz_chunk(row, cb)) =
        *(const i32x4*)(Qbase + (size_t)row * HD + cb * 8);
  }
  __syncthreads();
  int rA = wv * 16 + (lane & 15), qg = lane >> 4;
  bf16x8 qa0 = *(const bf16x8*)(Qp + swz_chunk(rA, qg));
  bf16x8 qa1 = *(const bf16x8*)(Qp + swz_chunk(rA, 4 + qg));
  float mrow[4], lrow[4];
  f32x4 o[4];
  #pragma unroll
  for (int j = 0; j < 4; ++j) { mrow[j] = -1e30f; lrow[j] = 0.f; }
  #pragma unroll
  for (int ct = 0; ct < 4; ++ct) o[ct] = (f32x4){0.f, 0.f, 0.f, 0.f};

  for (int kt = 0; kt < 64; ++kt) {
    int n0 = kt * 64;
    #pragma unroll
    for (int it = 0; it < 2; ++it) {
      int idx = it * 256 + tid, row = idx >> 3, cb = idx & 7;
      *(i32x4*)(Kq + swz_chunk(row, cb)) =
          *(const i32x4*)(K + ((size_t)bh * N + n0 + row) * HD + cb * 8);
      *(i32x4*)(Vq + swz_chunk(row, cb)) =
          *(const i32x4*)(Vt + ((size_t)bh * HD + row) * N + n0 + cb * 8);
    }
    __syncthreads();
    // S = Q K^T (Q pre-scaled by log2e/sqrt(C))
    f32x4 s[4];
    #pragma unroll
    for (int ct = 0; ct < 4; ++ct) {
      int br = ct * 16 + (lane & 15);
      bf16x8 b0 = *(const bf16x8*)(Kq + swz_chunk(br, qg));
      bf16x8 b1 = *(const bf16x8*)(Kq + swz_chunk(br, 4 + qg));
      s[ct] = mfma16(qa1, b1, mfma16(qa0, b0, (f32x4){0.f, 0.f, 0.f, 0.f}));
    }
    // online softmax (rows live in 16-lane groups: col=lane&15, row=(lane>>4)*4+j)
    #pragma unroll
    for (int j = 0; j < 4; ++j) {
      float tm = fmaxf(fmaxf(s[0][j], s[1][j]), fmaxf(s[2][j], s[3][j]));
      #pragma unroll
      for (int off = 1; off < 16; off <<= 1) tm = fmaxf(tm, __shfl_xor(tm, off));
      float nm = fmaxf(mrow[j], tm);
      float f = __builtin_amdgcn_exp2f(mrow[j] - nm);
      mrow[j] = nm;
      float rs = 0.f;
      #pragma unroll
      for (int ct = 0; ct < 4; ++ct) {
        float p = __builtin_amdgcn_exp2f(s[ct][j] - nm);
        s[ct][j] = p;
        rs += p;
      }
      #pragma unroll
      for (int off = 1; off < 16; off <<= 1) rs += __shfl_xor(rs, off);
      lrow[j] = lrow[j] * f + rs;
      #pragma unroll
      for (int ct = 0; ct < 4; ++ct) o[ct][j] *= f;
    }
    // P -> LDS (wave-private 16-row strip of Qp), then read back as A-frags
    #pragma unroll
    for (int ct = 0; ct < 4; ++ct) {
      int col = ct * 16 + (lane & 15);
      #pragma unroll
      for (int j = 0; j < 4; ++j) {
        int row = wv * 16 + (lane >> 4) * 4 + j;
        int byte = swz_chunk(row, col >> 3) + (col & 7) * 2;
        *(bf16_t*)(Qp + byte) = (bf16_t)s[ct][j];
      }
    }
    bf16x8 pa0 = *(const bf16x8*)(Qp + swz_chunk(rA, qg));
    bf16x8 pa1 = *(const bf16x8*)(Qp + swz_chunk(rA, 4 + qg));
    #pragma unroll
    for (int ct = 0; ct < 4; ++ct) {
      int br = ct * 16 + (lane & 15);
      bf16x8 v0 = *(const bf16x8*)(Vq + swz_chunk(br, qg));
      bf16x8 v1 = *(const bf16x8*)(Vq + swz_chunk(br, 4 + qg));
      o[ct] = mfma16(pa0, v0, o[ct]);
      o[ct] = mfma16(pa1, v1, o[ct]);
    }
    __syncthreads();
  }
  int b_ = bh >> 2, h = bh & 3;
  #pragma unroll
  for (int j = 0; j < 4; ++j) {
    float inv = 1.f / lrow[j];
    int token = q0 + wv * 16 + (lane >> 4) * 4 + j;
    size_t base = ((size_t)b_ * N + token) * C + h * HD;
    #pragma unroll
    for (int ct = 0; ct < 4; ++ct) {
      aout[base + ct * 16 + (lane & 15)] = (bf16_t)(o[ct][j] * inv);
    }
  }
}

// ---------------------------------------------------------------------------
// Kernel 5: proj GEMM + bias + residual, writes [B,C,H,W] fp32 with float4
// ---------------------------------------------------------------------------
__global__ __launch_bounds__(256, 4) void gemm_proj(
    const bf16_t* __restrict__ aout, const bf16_t* __restrict__ wT,
    const float* __restrict__ bias, const float* __restrict__ x,
    float* __restrict__ out) {
  __shared__ char smem[2 * 8192];
  char* As = smem;
  char* Bs = smem + 8192;
  int tid = threadIdx.x, lane = tid & 63, wv = tid >> 6;
  int mt = blockIdx.x & 255, nt = blockIdx.x >> 8;   // 256 x 4
  int m0 = mt * 64, c0 = nt * 64;
  f32x4 acc[4];
  #pragma unroll
  for (int i = 0; i < 4; ++i) acc[i] = (f32x4){0.f, 0.f, 0.f, 0.f};
  for (int kt = 0; kt < 4; ++kt) {
    int k0 = kt * 64;
    __syncthreads();
    #pragma unroll
    for (int it = 0; it < 2; ++it) {
      int idx = it * 256 + tid, row = idx >> 3, cb = idx & 7;
      *(i32x4*)(As + swz_chunk(row, cb)) =
          *(const i32x4*)(aout + (size_t)(m0 + row) * C + k0 + cb * 8);
      *(i32x4*)(Bs + swz_chunk(row, cb)) =
          *(const i32x4*)(wT + (size_t)(c0 + row) * C + k0 + cb * 8);
    }
    __syncthreads();
    int r = wv * 16 + (lane & 15), q = lane >> 4;
    bf16x8 a0 = *(const bf16x8*)(As + swz_chunk(r, q));
    bf16x8 a1 = *(const bf16x8*)(As + swz_chunk(r, 4 + q));
    #pragma unroll
    for (int ct = 0; ct < 4; ++ct) {
      int br = ct * 16 + (lane & 15);
      bf16x8 b0 = *(const bf16x8*)(Bs + swz_chunk(br, q));
      bf16x8 b1 = *(const bf16x8*)(Bs + swz_chunk(br, 4 + q));
      acc[ct] = mfma16(a0, b0, acc[ct]);
      acc[ct] = mfma16(a1, b1, acc[ct]);
    }
  }
  #pragma unroll
  for (int ct = 0; ct < 4; ++ct) {
    int c = c0 + ct * 16 + (lane & 15);
    float bv = bias[c];
    int m = m0 + wv * 16 + (lane >> 4) * 4;   // 4 consecutive tokens
    int b_ = m >> 12, n = m & 4095;
    size_t off = ((size_t)(b_ * C + c)) * N + n;
    f32x4 xin = *(const f32x4*)(x + off);
    f32x4 res;
    #pragma unroll
    for (int j = 0; j < 4; ++j) res[j] = xin[j] + acc[ct][j] + bv;
    *(f32x4*)(out + off) = res;
  }
}

// ---------------------------------------------------------------------------
extern "C" void kernel_launch(void* const* d_in, const int* in_sizes, int n_in,
                              void* d_out, int out_size, void* d_ws, size_t ws_size,
                              hipStream_t stream) {
  const float* x     = (const float*)d_in[0];
  const float* gam   = (const float*)d_in[1];
  const float* bet   = (const float*)d_in[2];
  const float* wqkv  = (const float*)d_in[3];
  const float* bqkv  = (const float*)d_in[4];
  const float* wproj = (const float*)d_in[5];
  const float* bproj = (const float*)d_in[6];
  float* out = (float*)d_out;

  char* ws = (char*)d_ws;
  size_t off = 0;
  auto alloc = [&](size_t bytes) {
    void* p = ws + off;
    off += (bytes + 255) & ~(size_t)255;
    return p;
  };
  bf16_t* xn     = (bf16_t*)alloc((size_t)Bb * N * C * 2);
  bf16_t* wqkvT  = (bf16_t*)alloc((size_t)768 * 256 * 2);
  bf16_t* wprojT = (bf16_t*)alloc((size_t)256 * 256 * 2);
  bf16_t* Qb     = (bf16_t*)alloc((size_t)Bb * NH * N * HD * 2);
  bf16_t* Kb     = (bf16_t*)alloc((size_t)Bb * NH * N * HD * 2);
  bf16_t* Vtb    = (bf16_t*)alloc((size_t)Bb * NH * HD * N * 2);
  bf16_t* aout   = (bf16_t*)alloc((size_t)Bb * N * C * 2);
  if (ws_size < off) return;   // workspace too small: fail loudly via poisoned out

  hipLaunchKernelGGL(ln_kernel, dim3(Bb * 64), dim3(256), 0, stream, x, gam, bet, xn);
  hipLaunchKernelGGL(conv_w, dim3(768), dim3(256), 0, stream, wqkv, wproj, wqkvT, wprojT);
  hipLaunchKernelGGL(gemm_qkv, dim3(256 * 12), dim3(256), 0, stream, xn, wqkvT, bqkv,
                     Qb, Kb, Vtb);
  hipLaunchKernelGGL(attn_kernel, dim3(Bb * NH * 64), dim3(256), 0, stream,
                     Qb, Kb, Vtb, aout);
  hipLaunchKernelGGL(gemm_proj, dim3(256 * 4), dim3(256), 0, stream, aout, wprojT,
                     bproj, x, out);
}

// Round 3
// 260.709 us; speedup vs baseline: 1.2497x; 1.2497x over previous
//
#include <hip/hip_runtime.h>
#include <hip/hip_bf16.h>

typedef __bf16 bf16_t;
typedef bf16_t bf16x8 __attribute__((ext_vector_type(8)));
typedef bf16_t bf16x4v __attribute__((ext_vector_type(4)));
typedef float f32x4 __attribute__((ext_vector_type(4)));
typedef int i32x4 __attribute__((ext_vector_type(4)));

constexpr int C = 256;
constexpr int Bb = 4;
constexpr int N = 4096;   // 64*64 tokens per batch
constexpr int NH = 4;
constexpr int HD = 64;
// fold (1/sqrt(C)) * log2(e) into Q so softmax uses exp2 directly
constexpr float SM_SCALE_LOG2E = 0.0625f * 1.44269504088896340736f;

// byte offset of 16B chunk `chunk` in row `row` of a [rows][64 bf16] LDS tile,
// XOR-swizzled to kill the 128B-row-stride bank conflict (guide G4 / T2)
__device__ __forceinline__ int swz_chunk(int row, int chunk) {
  return row * 128 + ((chunk ^ (row & 7)) << 4);
}

__device__ __forceinline__ f32x4 mfma16(bf16x8 a, bf16x8 b, f32x4 c) {
  return __builtin_amdgcn_mfma_f32_16x16x32_bf16(a, b, c, 0, 0, 0);
}

// ---------------------------------------------------------------------------
// Kernel 1: LayerNorm over C with [B,C,N] -> [B,N,C] transpose, bf16 out
// ---------------------------------------------------------------------------
__global__ __launch_bounds__(256, 2) void ln_kernel(
    const float* __restrict__ x, const float* __restrict__ gamma,
    const float* __restrict__ beta, bf16_t* __restrict__ xn) {
  __shared__ float tile[256][65];       // [channel][token], padded
  __shared__ float red[2][4][64];
  __shared__ float mu_s[64], rs_s[64];
  int tid = threadIdx.x, lane = tid & 63, wv = tid >> 6;
  int b = blockIdx.x >> 6;
  int n0 = (blockIdx.x & 63) << 6;
  const float* xb = x + ((size_t)b * C) * N + n0;
  #pragma unroll 4
  for (int i = 0; i < 64; ++i) {
    int c = wv * 64 + i;
    tile[c][lane] = xb[(size_t)c * N + lane];   // coalesced along tokens
  }
  __syncthreads();
  // token = lane, channel-quarter = wv
  float s = 0.f, s2 = 0.f;
  #pragma unroll 8
  for (int i = 0; i < 64; ++i) {
    float v = tile[wv * 64 + i][lane];
    s += v; s2 += v * v;
  }
  red[0][wv][lane] = s; red[1][wv][lane] = s2;
  __syncthreads();
  if (tid < 64) {
    float ts  = red[0][0][tid] + red[0][1][tid] + red[0][2][tid] + red[0][3][tid];
    float ts2 = red[1][0][tid] + red[1][1][tid] + red[1][2][tid] + red[1][3][tid];
    float mu  = ts * (1.f / 256.f);
    float var = fmaxf(ts2 * (1.f / 256.f) - mu * mu, 0.f);
    mu_s[tid] = mu;
    rs_s[tid] = rsqrtf(var + 1e-5f);
  }
  __syncthreads();
  float g = gamma[tid], be = beta[tid];
  bf16_t* xo = xn + ((size_t)(b * N + n0)) * C + tid;
  #pragma unroll 4
  for (int i = 0; i < 64; ++i) {
    float v = (tile[tid][i] - mu_s[i]) * rs_s[i] * g + be;
    xo[(size_t)i * C] = (bf16_t)v;     // coalesced along channels
  }
}

// ---------------------------------------------------------------------------
// Kernel 2: weights -> bf16, transposed to B^T layout [ncol][k]
// ---------------------------------------------------------------------------
__global__ void conv_w(const float* __restrict__ wqkv, const float* __restrict__ wproj,
                       bf16_t* __restrict__ wqkvT, bf16_t* __restrict__ wprojT) {
  int id = blockIdx.x * 256 + threadIdx.x;
  if (id < 768 * 256) {
    int nn = id >> 8, kk = id & 255;
    wqkvT[id] = (bf16_t)wqkv[(size_t)kk * 768 + nn];
  }
  if (id < 256 * 256) {
    int nn = id >> 8, kk = id & 255;
    wprojT[id] = (bf16_t)wproj[(size_t)kk * 256 + nn];
  }
}

// ---------------------------------------------------------------------------
// Kernel 3: QKV GEMM  xn[16384,256] @ w[256,768] + b  -> Q (scaled), K, Vt
// ---------------------------------------------------------------------------
__global__ __launch_bounds__(256, 4) void gemm_qkv(
    const bf16_t* __restrict__ xn, const bf16_t* __restrict__ wT,
    const float* __restrict__ bias,
    bf16_t* __restrict__ Q, bf16_t* __restrict__ K, bf16_t* __restrict__ Vt) {
  __shared__ char smem[2 * 8192];
  char* As = smem;            // [64 m][64 k] bf16 swizzled
  char* Bs = smem + 8192;     // [64 n][64 k]
  int tid = threadIdx.x, lane = tid & 63, wv = tid >> 6;
  int mt = blockIdx.x & 255, nt = blockIdx.x >> 8;   // 256 x 12
  int m0 = mt * 64, ncol0 = nt * 64;
  f32x4 acc[4];
  #pragma unroll
  for (int i = 0; i < 4; ++i) acc[i] = (f32x4){0.f, 0.f, 0.f, 0.f};
  for (int kt = 0; kt < 4; ++kt) {
    int k0 = kt * 64;
    __syncthreads();
    #pragma unroll
    for (int it = 0; it < 2; ++it) {
      int idx = it * 256 + tid, row = idx >> 3, cb = idx & 7;
      *(i32x4*)(As + swz_chunk(row, cb)) =
          *(const i32x4*)(xn + (size_t)(m0 + row) * C + k0 + cb * 8);
      *(i32x4*)(Bs + swz_chunk(row, cb)) =
          *(const i32x4*)(wT + (size_t)(ncol0 + row) * C + k0 + cb * 8);
    }
    __syncthreads();
    int r = wv * 16 + (lane & 15), q = lane >> 4;
    bf16x8 a0 = *(const bf16x8*)(As + swz_chunk(r, q));
    bf16x8 a1 = *(const bf16x8*)(As + swz_chunk(r, 4 + q));
    #pragma unroll
    for (int ct = 0; ct < 4; ++ct) {
      int br = ct * 16 + (lane & 15);
      bf16x8 b0 = *(const bf16x8*)(Bs + swz_chunk(br, q));
      bf16x8 b1 = *(const bf16x8*)(Bs + swz_chunk(br, 4 + q));
      acc[ct] = mfma16(a0, b0, acc[ct]);
      acc[ct] = mfma16(a1, b1, acc[ct]);
    }
  }
  #pragma unroll
  for (int ct = 0; ct < 4; ++ct) {
    int cg = ncol0 + ct * 16 + (lane & 15);
    float bv = bias[cg];
    int sect = cg >> 8;          // 0=q, 1=k, 2=v
    int cc = cg & 255;
    int h = cc >> 6, d = cc & 63;
    #pragma unroll
    for (int j = 0; j < 4; ++j) {
      int m = m0 + wv * 16 + (lane >> 4) * 4 + j;
      int b_ = m >> 12, n = m & 4095;
      float v = acc[ct][j] + bv;
      if (sect == 0) {
        Q[((size_t)((b_ * NH + h) * N + n)) * HD + d] = (bf16_t)(v * SM_SCALE_LOG2E);
      } else if (sect == 1) {
        K[((size_t)((b_ * NH + h) * N + n)) * HD + d] = (bf16_t)v;
      } else {
        Vt[((size_t)((b_ * NH + h) * HD + d)) * N + n] = (bf16_t)v;  // V transposed
      }
    }
  }
}

// ---------------------------------------------------------------------------
// Kernel 4: flash attention — SWAPPED operands (S^T = K·Q^T, O^T = V^T·P^T)
// so the k-reduction is mostly lane-local and the rescale is fully lane-local.
// One 64-row Q tile per block, 4 waves x 16 q-rows.
// ---------------------------------------------------------------------------
__global__ __launch_bounds__(256, 4) void attn_kernel(
    const bf16_t* __restrict__ Q, const bf16_t* __restrict__ K,
    const bf16_t* __restrict__ Vt, bf16_t* __restrict__ aout) {
  __shared__ char smem[3 * 8192];
  char* Kq = smem;             // [64 tok][64 hd]
  char* Vq = smem + 8192;      // [64 hd][64 tok]  (V^T)
  char* Qp = smem + 16384;     // Q tile, then reused per-wave strip for P [q][k]
  int tid = threadIdx.x, lane = tid & 63, wv = tid >> 6;
  int bh = blockIdx.x >> 6, qt = blockIdx.x & 63;
  int q0 = qt * 64;
  const bf16_t* Qbase = Q + ((size_t)bh * N + q0) * HD;
  #pragma unroll
  for (int it = 0; it < 2; ++it) {
    int idx = it * 256 + tid, row = idx >> 3, cb = idx & 7;
    *(i32x4*)(Qp + swz_chunk(row, cb)) =
        *(const i32x4*)(Qbase + (size_t)row * HD + cb * 8);
  }
  __syncthreads();
  int rA = wv * 16 + (lane & 15);   // this lane's q-row (tile-local)
  int qg = lane >> 4;               // k-chunk group
  // B-frag for S^T = K·Q^T : rows of Q (k-dim = hd)
  bf16x8 qb0 = *(const bf16x8*)(Qp + swz_chunk(rA, qg));
  bf16x8 qb1 = *(const bf16x8*)(Qp + swz_chunk(rA, 4 + qg));

  float m_r = -1e30f, l_r = 0.f;    // per-lane: stats for q = rA
  f32x4 o[4];
  #pragma unroll
  for (int ct = 0; ct < 4; ++ct) o[ct] = (f32x4){0.f, 0.f, 0.f, 0.f};

  for (int kt = 0; kt < 64; ++kt) {
    int n0 = kt * 64;
    #pragma unroll
    for (int it = 0; it < 2; ++it) {
      int idx = it * 256 + tid, row = idx >> 3, cb = idx & 7;
      *(i32x4*)(Kq + swz_chunk(row, cb)) =
          *(const i32x4*)(K + ((size_t)bh * N + n0 + row) * HD + cb * 8);
      *(i32x4*)(Vq + swz_chunk(row, cb)) =
          *(const i32x4*)(Vt + ((size_t)bh * HD + row) * N + n0 + cb * 8);
    }
    __syncthreads();
    // S^T[k][q]: A = K rows (k tokens), B = Q rows (this wave's 16 q)
    // s[ct][j] = S^T[k = ct*16 + qg*4 + j][q = rA]
    f32x4 s[4];
    #pragma unroll
    for (int ct = 0; ct < 4; ++ct) {
      int ar = ct * 16 + (lane & 15);
      bf16x8 ka0 = *(const bf16x8*)(Kq + swz_chunk(ar, qg));
      bf16x8 ka1 = *(const bf16x8*)(Kq + swz_chunk(ar, 4 + qg));
      s[ct] = mfma16(ka1, qb1, mfma16(ka0, qb0, (f32x4){0.f, 0.f, 0.f, 0.f}));
    }
    // online softmax: 16 lane-local values + 2 shfl (lanes q, q+16, q+32, q+48)
    float tm = fmaxf(fmaxf(fmaxf(s[0][0], s[0][1]), fmaxf(s[0][2], s[0][3])),
                     fmaxf(fmaxf(s[1][0], s[1][1]), fmaxf(s[1][2], s[1][3])));
    tm = fmaxf(tm, fmaxf(fmaxf(fmaxf(s[2][0], s[2][1]), fmaxf(s[2][2], s[2][3])),
                         fmaxf(fmaxf(s[3][0], s[3][1]), fmaxf(s[3][2], s[3][3]))));
    tm = fmaxf(tm, __shfl_xor(tm, 16));
    tm = fmaxf(tm, __shfl_xor(tm, 32));
    float nm = fmaxf(m_r, tm);
    float f = __builtin_amdgcn_exp2f(m_r - nm);
    m_r = nm;
    float rs = 0.f;
    #pragma unroll
    for (int ct = 0; ct < 4; ++ct) {
      #pragma unroll
      for (int j = 0; j < 4; ++j) {
        float p = __builtin_amdgcn_exp2f(s[ct][j] - nm);
        s[ct][j] = p;
        rs += p;
      }
    }
    rs += __shfl_xor(rs, 16);
    rs += __shfl_xor(rs, 32);
    l_r = l_r * f + rs;
    #pragma unroll
    for (int ct = 0; ct < 4; ++ct) {
      o[ct][0] *= f; o[ct][1] *= f; o[ct][2] *= f; o[ct][3] *= f;
    }
    // P -> LDS wave strip as [q][k]: lane writes 4 consecutive k (8B packed)
    #pragma unroll
    for (int ct = 0; ct < 4; ++ct) {
      bf16x4v pk;
      pk[0] = (bf16_t)s[ct][0]; pk[1] = (bf16_t)s[ct][1];
      pk[2] = (bf16_t)s[ct][2]; pk[3] = (bf16_t)s[ct][3];
      // k = ct*16 + qg*4 + j  ->  chunk 2ct + (qg>>1), sub-offset (qg&1)*8
      *(bf16x4v*)(Qp + swz_chunk(rA, 2 * ct + (qg >> 1)) + (qg & 1) * 8) = pk;
    }
    // O^T += V^T · P^T : A = V^T rows (hd), B = P rows (q); wave-private RAW,
    // compiler inserts lgkmcnt — no barrier needed.
    bf16x8 pb0 = *(const bf16x8*)(Qp + swz_chunk(rA, qg));
    bf16x8 pb1 = *(const bf16x8*)(Qp + swz_chunk(rA, 4 + qg));
    #pragma unroll
    for (int ct = 0; ct < 4; ++ct) {
      int vr = ct * 16 + (lane & 15);
      bf16x8 va0 = *(const bf16x8*)(Vq + swz_chunk(vr, qg));
      bf16x8 va1 = *(const bf16x8*)(Vq + swz_chunk(vr, 4 + qg));
      o[ct] = mfma16(va1, pb1, mfma16(va0, pb0, o[ct]));
    }
    __syncthreads();
  }
  // epilogue: o[ct][j] = O^T[hd = ct*16 + qg*4 + j][q = rA]
  int b_ = bh >> 2, h = bh & 3;
  float inv = 1.f / l_r;
  int token = q0 + rA;
  size_t base = ((size_t)b_ * N + token) * C + h * HD;
  #pragma unroll
  for (int ct = 0; ct < 4; ++ct) {
    bf16x4v ov;
    ov[0] = (bf16_t)(o[ct][0] * inv); ov[1] = (bf16_t)(o[ct][1] * inv);
    ov[2] = (bf16_t)(o[ct][2] * inv); ov[3] = (bf16_t)(o[ct][3] * inv);
    *(bf16x4v*)(aout + base + ct * 16 + qg * 4) = ov;
  }
}

// ---------------------------------------------------------------------------
// Kernel 5: proj GEMM + bias + residual, writes [B,C,H,W] fp32 with float4
// ---------------------------------------------------------------------------
__global__ __launch_bounds__(256, 4) void gemm_proj(
    const bf16_t* __restrict__ aout, const bf16_t* __restrict__ wT,
    const float* __restrict__ bias, const float* __restrict__ x,
    float* __restrict__ out) {
  __shared__ char smem[2 * 8192];
  char* As = smem;
  char* Bs = smem + 8192;
  int tid = threadIdx.x, lane = tid & 63, wv = tid >> 6;
  int mt = blockIdx.x & 255, nt = blockIdx.x >> 8;   // 256 x 4
  int m0 = mt * 64, c0 = nt * 64;
  f32x4 acc[4];
  #pragma unroll
  for (int i = 0; i < 4; ++i) acc[i] = (f32x4){0.f, 0.f, 0.f, 0.f};
  for (int kt = 0; kt < 4; ++kt) {
    int k0 = kt * 64;
    __syncthreads();
    #pragma unroll
    for (int it = 0; it < 2; ++it) {
      int idx = it * 256 + tid, row = idx >> 3, cb = idx & 7;
      *(i32x4*)(As + swz_chunk(row, cb)) =
          *(const i32x4*)(aout + (size_t)(m0 + row) * C + k0 + cb * 8);
      *(i32x4*)(Bs + swz_chunk(row, cb)) =
          *(const i32x4*)(wT + (size_t)(c0 + row) * C + k0 + cb * 8);
    }
    __syncthreads();
    int r = wv * 16 + (lane & 15), q = lane >> 4;
    bf16x8 a0 = *(const bf16x8*)(As + swz_chunk(r, q));
    bf16x8 a1 = *(const bf16x8*)(As + swz_chunk(r, 4 + q));
    #pragma unroll
    for (int ct = 0; ct < 4; ++ct) {
      int br = ct * 16 + (lane & 15);
      bf16x8 b0 = *(const bf16x8*)(Bs + swz_chunk(br, q));
      bf16x8 b1 = *(const bf16x8*)(Bs + swz_chunk(br, 4 + q));
      acc[ct] = mfma16(a0, b0, acc[ct]);
      acc[ct] = mfma16(a1, b1, acc[ct]);
    }
  }
  #pragma unroll
  for (int ct = 0; ct < 4; ++ct) {
    int c = c0 + ct * 16 + (lane & 15);
    float bv = bias[c];
    int m = m0 + wv * 16 + (lane >> 4) * 4;   // 4 consecutive tokens
    int b_ = m >> 12, n = m & 4095;
    size_t off = ((size_t)(b_ * C + c)) * N + n;
    f32x4 xin = *(const f32x4*)(x + off);
    f32x4 res;
    #pragma unroll
    for (int j = 0; j < 4; ++j) res[j] = xin[j] + acc[ct][j] + bv;
    *(f32x4*)(out + off) = res;
  }
}

// ---------------------------------------------------------------------------
extern "C" void kernel_launch(void* const* d_in, const int* in_sizes, int n_in,
                              void* d_out, int out_size, void* d_ws, size_t ws_size,
                              hipStream_t stream) {
  const float* x     = (const float*)d_in[0];
  const float* gam   = (const float*)d_in[1];
  const float* bet   = (const float*)d_in[2];
  const float* wqkv  = (const float*)d_in[3];
  const float* bqkv  = (const float*)d_in[4];
  const float* wproj = (const float*)d_in[5];
  const float* bproj = (const float*)d_in[6];
  float* out = (float*)d_out;

  char* ws = (char*)d_ws;
  size_t off = 0;
  auto alloc = [&](size_t bytes) {
    void* p = ws + off;
    off += (bytes + 255) & ~(size_t)255;
    return p;
  };
  bf16_t* xn     = (bf16_t*)alloc((size_t)Bb * N * C * 2);
  bf16_t* wqkvT  = (bf16_t*)alloc((size_t)768 * 256 * 2);
  bf16_t* wprojT = (bf16_t*)alloc((size_t)256 * 256 * 2);
  bf16_t* Qb     = (bf16_t*)alloc((size_t)Bb * NH * N * HD * 2);
  bf16_t* Kb     = (bf16_t*)alloc((size_t)Bb * NH * N * HD * 2);
  bf16_t* Vtb    = (bf16_t*)alloc((size_t)Bb * NH * HD * N * 2);
  bf16_t* aout   = (bf16_t*)alloc((size_t)Bb * N * C * 2);
  if (ws_size < off) return;   // workspace too small: fail loudly via poisoned out

  hipLaunchKernelGGL(ln_kernel, dim3(Bb * 64), dim3(256), 0, stream, x, gam, bet, xn);
  hipLaunchKernelGGL(conv_w, dim3(768), dim3(256), 0, stream, wqkv, wproj, wqkvT, wprojT);
  hipLaunchKernelGGL(gemm_qkv, dim3(256 * 12), dim3(256), 0, stream, xn, wqkvT, bqkv,
                     Qb, Kb, Vtb);
  hipLaunchKernelGGL(attn_kernel, dim3(Bb * NH * 64), dim3(256), 0, stream,
                     Qb, Kb, Vtb, aout);
  hipLaunchKernelGGL(gemm_proj, dim3(256 * 4), dim3(256), 0, stream, aout, wprojT,
                     bproj, x, out);
}

// Round 4
// 214.817 us; speedup vs baseline: 1.5167x; 1.2136x over previous
//
#include <hip/hip_runtime.h>
#include <hip/hip_bf16.h>

typedef __bf16 bf16_t;
typedef bf16_t bf16x8 __attribute__((ext_vector_type(8)));
typedef bf16_t bf16x4v __attribute__((ext_vector_type(4)));
typedef float f32x4 __attribute__((ext_vector_type(4)));
typedef float f32x16 __attribute__((ext_vector_type(16)));
typedef int i32x4 __attribute__((ext_vector_type(4)));

constexpr int C = 256;
constexpr int Bb = 4;
constexpr int N = 4096;   // 64*64 tokens per batch
constexpr int NH = 4;
constexpr int HD = 64;
// fold (1/sqrt(C)) * log2(e) into Q so softmax uses exp2 directly
constexpr float SM_SCALE_LOG2E = 0.0625f * 1.44269504088896340736f;

// byte offset of 16B chunk `chunk` in row `row` of a [rows][64 bf16] LDS tile,
// XOR-swizzled to kill the 128B-row-stride bank conflict (guide G4 / T2)
__device__ __forceinline__ int swz_chunk(int row, int chunk) {
  return row * 128 + ((chunk ^ (row & 7)) << 4);
}

__device__ __forceinline__ f32x4 mfma16(bf16x8 a, bf16x8 b, f32x4 c) {
  return __builtin_amdgcn_mfma_f32_16x16x32_bf16(a, b, c, 0, 0, 0);
}
__device__ __forceinline__ f32x16 mfma32(bf16x8 a, bf16x8 b, f32x16 c) {
  return __builtin_amdgcn_mfma_f32_32x32x16_bf16(a, b, c, 0, 0, 0);
}

// ---------------------------------------------------------------------------
// Kernel 1: LayerNorm over C with [B,C,N] -> [B,N,C] transpose, bf16 out
// ---------------------------------------------------------------------------
__global__ __launch_bounds__(256, 2) void ln_kernel(
    const float* __restrict__ x, const float* __restrict__ gamma,
    const float* __restrict__ beta, bf16_t* __restrict__ xn) {
  __shared__ float tile[256][65];       // [channel][token], padded
  __shared__ float red[2][4][64];
  __shared__ float mu_s[64], rs_s[64];
  int tid = threadIdx.x, lane = tid & 63, wv = tid >> 6;
  int b = blockIdx.x >> 6;
  int n0 = (blockIdx.x & 63) << 6;
  const float* xb = x + ((size_t)b * C) * N + n0;
  #pragma unroll 4
  for (int i = 0; i < 64; ++i) {
    int c = wv * 64 + i;
    tile[c][lane] = xb[(size_t)c * N + lane];   // coalesced along tokens
  }
  __syncthreads();
  // token = lane, channel-quarter = wv
  float s = 0.f, s2 = 0.f;
  #pragma unroll 8
  for (int i = 0; i < 64; ++i) {
    float v = tile[wv * 64 + i][lane];
    s += v; s2 += v * v;
  }
  red[0][wv][lane] = s; red[1][wv][lane] = s2;
  __syncthreads();
  if (tid < 64) {
    float ts  = red[0][0][tid] + red[0][1][tid] + red[0][2][tid] + red[0][3][tid];
    float ts2 = red[1][0][tid] + red[1][1][tid] + red[1][2][tid] + red[1][3][tid];
    float mu  = ts * (1.f / 256.f);
    float var = fmaxf(ts2 * (1.f / 256.f) - mu * mu, 0.f);
    mu_s[tid] = mu;
    rs_s[tid] = rsqrtf(var + 1e-5f);
  }
  __syncthreads();
  float g = gamma[tid], be = beta[tid];
  bf16_t* xo = xn + ((size_t)(b * N + n0)) * C + tid;
  #pragma unroll 4
  for (int i = 0; i < 64; ++i) {
    float v = (tile[tid][i] - mu_s[i]) * rs_s[i] * g + be;
    xo[(size_t)i * C] = (bf16_t)v;     // coalesced along channels
  }
}

// ---------------------------------------------------------------------------
// Kernel 2: weights -> bf16, transposed to B^T layout [ncol][k]
// ---------------------------------------------------------------------------
__global__ void conv_w(const float* __restrict__ wqkv, const float* __restrict__ wproj,
                       bf16_t* __restrict__ wqkvT, bf16_t* __restrict__ wprojT) {
  int id = blockIdx.x * 256 + threadIdx.x;
  if (id < 768 * 256) {
    int nn = id >> 8, kk = id & 255;
    wqkvT[id] = (bf16_t)wqkv[(size_t)kk * 768 + nn];
  }
  if (id < 256 * 256) {
    int nn = id >> 8, kk = id & 255;
    wprojT[id] = (bf16_t)wproj[(size_t)kk * 256 + nn];
  }
}

// ---------------------------------------------------------------------------
// Kernel 3: QKV GEMM  xn[16384,256] @ w[256,768] + b  -> Q (scaled), K, Vt
// ---------------------------------------------------------------------------
__global__ __launch_bounds__(256, 4) void gemm_qkv(
    const bf16_t* __restrict__ xn, const bf16_t* __restrict__ wT,
    const float* __restrict__ bias,
    bf16_t* __restrict__ Q, bf16_t* __restrict__ K, bf16_t* __restrict__ Vt) {
  __shared__ char smem[2 * 8192];
  char* As = smem;            // [64 m][64 k] bf16 swizzled
  char* Bs = smem + 8192;     // [64 n][64 k]
  int tid = threadIdx.x, lane = tid & 63, wv = tid >> 6;
  int mt = blockIdx.x & 255, nt = blockIdx.x >> 8;   // 256 x 12
  int m0 = mt * 64, ncol0 = nt * 64;
  f32x4 acc[4];
  #pragma unroll
  for (int i = 0; i < 4; ++i) acc[i] = (f32x4){0.f, 0.f, 0.f, 0.f};
  for (int kt = 0; kt < 4; ++kt) {
    int k0 = kt * 64;
    __syncthreads();
    #pragma unroll
    for (int it = 0; it < 2; ++it) {
      int idx = it * 256 + tid, row = idx >> 3, cb = idx & 7;
      *(i32x4*)(As + swz_chunk(row, cb)) =
          *(const i32x4*)(xn + (size_t)(m0 + row) * C + k0 + cb * 8);
      *(i32x4*)(Bs + swz_chunk(row, cb)) =
          *(const i32x4*)(wT + (size_t)(ncol0 + row) * C + k0 + cb * 8);
    }
    __syncthreads();
    int r = wv * 16 + (lane & 15), q = lane >> 4;
    bf16x8 a0 = *(const bf16x8*)(As + swz_chunk(r, q));
    bf16x8 a1 = *(const bf16x8*)(As + swz_chunk(r, 4 + q));
    #pragma unroll
    for (int ct = 0; ct < 4; ++ct) {
      int br = ct * 16 + (lane & 15);
      bf16x8 b0 = *(const bf16x8*)(Bs + swz_chunk(br, q));
      bf16x8 b1 = *(const bf16x8*)(Bs + swz_chunk(br, 4 + q));
      acc[ct] = mfma16(a0, b0, acc[ct]);
      acc[ct] = mfma16(a1, b1, acc[ct]);
    }
  }
  #pragma unroll
  for (int ct = 0; ct < 4; ++ct) {
    int cg = ncol0 + ct * 16 + (lane & 15);
    float bv = bias[cg];
    int sect = cg >> 8;          // 0=q, 1=k, 2=v
    int cc = cg & 255;
    int h = cc >> 6, d = cc & 63;
    #pragma unroll
    for (int j = 0; j < 4; ++j) {
      int m = m0 + wv * 16 + (lane >> 4) * 4 + j;
      int b_ = m >> 12, n = m & 4095;
      float v = acc[ct][j] + bv;
      if (sect == 0) {
        Q[((size_t)((b_ * NH + h) * N + n)) * HD + d] = (bf16_t)(v * SM_SCALE_LOG2E);
      } else if (sect == 1) {
        K[((size_t)((b_ * NH + h) * N + n)) * HD + d] = (bf16_t)v;
      } else {
        Vt[((size_t)((b_ * NH + h) * HD + d)) * N + n] = (bf16_t)v;  // V transposed
      }
    }
  }
}

// ---------------------------------------------------------------------------
// Kernel 4: flash attention v3 — 32x32x16 MFMA, swapped operands.
// 512 threads = 8 waves = 4 q-groups x 2 k-parities; QBLK=128, KVBLK=64/parity.
// Each wave: 32 q rows, alternate K/V tiles; parity partners merge at end.
// ---------------------------------------------------------------------------
__global__ __launch_bounds__(512, 4) void attn_kernel(
    const bf16_t* __restrict__ Q, const bf16_t* __restrict__ K,
    const bf16_t* __restrict__ Vt, bf16_t* __restrict__ aout) {
  __shared__ char smem[65536];
  // [0,8K) K-even | [8K,16K) V-even | [16K,24K) K-odd | [24K,32K) V-odd
  // [32K,64K) P strips (4KB/wave); Q tile (16KB) overlays strips 0-3 at start
  char* tiles = smem;
  char* QP = smem + 32768;
  int tid = threadIdx.x, lane = tid & 63, wv = tid >> 6;
  int hi = lane >> 5, qL = lane & 31;
  int wq = wv >> 1, par = wv & 1;
  int bh = blockIdx.x >> 5, qt = blockIdx.x & 31;
  int q0 = qt * 128;

  // load Q tile (128 q x 64 hd) into QP[0,16K)
  const bf16_t* Qbase = Q + ((size_t)bh * N + q0) * HD;
  #pragma unroll
  for (int it = 0; it < 2; ++it) {
    int idx = it * 512 + tid;          // 1024 chunks of 16B
    int row = idx >> 3, cb = idx & 7;
    *(i32x4*)(QP + swz_chunk(row, cb)) =
        *(const i32x4*)(Qbase + (size_t)row * HD + cb * 8);
  }
  __syncthreads();
  // Q b-frags: row = wq*32+qL, k-slice hd = hs*16 + hi*8 + i
  bf16x8 qb[4];
  #pragma unroll
  for (int hs = 0; hs < 4; ++hs)
    qb[hs] = *(const bf16x8*)(QP + swz_chunk(wq * 32 + qL, hs * 2 + hi));
  // (no extra barrier: first P-write happens after the post-staging barrier,
  //  by which time every wave's Q-frag ds_reads have drained)

  char* kbase = tiles + par * 16384;
  char* vbase = kbase + 8192;
  char* pstrip = QP + wv * 4096;       // P strip: [32 q][64 tok] bf16 swizzled
  const bf16_t* Kbh = K + (size_t)bh * N * HD;
  const bf16_t* Vbh = Vt + (size_t)bh * HD * N;

  float m_r = -3.0e38f, l_r = 0.f;     // per-lane stats for q = q0+wq*32+qL
  f32x16 o0, o1;                       // O^T: hd = hdb*32 + (r&3)+8*(r>>2)+4*hi
  #pragma unroll
  for (int i = 0; i < 16; ++i) { o0[i] = 0.f; o1[i] = 0.f; }

  int srow = tid >> 3, scb = tid & 7;  // staging: 64B/thread
  for (int adv = 0; adv < 32; ++adv) {
    int n0 = adv * 128;
    // stage 4 x 8KB tiles (buf == it: 512 chunks each)
    {
      const bf16_t* s0p = Kbh + (size_t)(n0 + srow) * HD + scb * 8;
      const bf16_t* s1p = Vbh + (size_t)srow * N + n0 + scb * 8;
      const bf16_t* s2p = Kbh + (size_t)(n0 + 64 + srow) * HD + scb * 8;
      const bf16_t* s3p = Vbh + (size_t)srow * N + n0 + 64 + scb * 8;
      int d = swz_chunk(srow, scb);
      *(i32x4*)(tiles + d)         = *(const i32x4*)s0p;
      *(i32x4*)(tiles + 8192 + d)  = *(const i32x4*)s1p;
      *(i32x4*)(tiles + 16384 + d) = *(const i32x4*)s2p;
      *(i32x4*)(tiles + 24576 + d) = *(const i32x4*)s3p;
    }
    __syncthreads();
    // S^T = K(32 tok) x Q(32 q), two token-blocks kb=0,1
    f32x16 s0, s1;
    #pragma unroll
    for (int i = 0; i < 16; ++i) { s0[i] = 0.f; s1[i] = 0.f; }
    #pragma unroll
    for (int hs = 0; hs < 4; ++hs) {
      bf16x8 ka0 = *(const bf16x8*)(kbase + swz_chunk(qL, hs * 2 + hi));
      bf16x8 ka1 = *(const bf16x8*)(kbase + swz_chunk(32 + qL, hs * 2 + hi));
      s0 = mfma32(ka0, qb[hs], s0);
      s1 = mfma32(ka1, qb[hs], s1);
    }
    // online softmax: 32 lane-local values + 1 shfl pair (lane ^ 32)
    float tm = s0[0];
    #pragma unroll
    for (int i = 1; i < 16; ++i) tm = fmaxf(tm, s0[i]);
    #pragma unroll
    for (int i = 0; i < 16; ++i) tm = fmaxf(tm, s1[i]);
    tm = fmaxf(tm, __shfl_xor(tm, 32));
    float nm = fmaxf(m_r, tm);
    if (!__all(nm == m_r)) {           // exact defer: rescale only on growth
      float f = __builtin_amdgcn_exp2f(m_r - nm);
      l_r *= f;
      o0 *= f; o1 *= f;
      m_r = nm;
    }
    float rs = 0.f;
    #pragma unroll
    for (int i = 0; i < 16; ++i) {
      float p = __builtin_amdgcn_exp2f(s0[i] - m_r); s0[i] = p; rs += p;
    }
    #pragma unroll
    for (int i = 0; i < 16; ++i) {
      float p = __builtin_amdgcn_exp2f(s1[i] - m_r); s1[i] = p; rs += p;
    }
    rs += __shfl_xor(rs, 32);
    l_r += rs;
    // P -> wave strip [32 q][64 tok]: reg 4g..4g+3 = tokens kb*32+8g+4hi+{0..3}
    #pragma unroll
    for (int g = 0; g < 4; ++g) {
      bf16x4v p0, p1;
      #pragma unroll
      for (int j = 0; j < 4; ++j) {
        p0[j] = (bf16_t)s0[g * 4 + j];
        p1[j] = (bf16_t)s1[g * 4 + j];
      }
      *(bf16x4v*)(pstrip + swz_chunk(qL, g) + hi * 8) = p0;
      *(bf16x4v*)(pstrip + swz_chunk(qL, 4 + g) + hi * 8) = p1;
    }
    // O^T += V^T(32 hd) x P(32 q) over 64 tokens (wave-private RAW in LDS)
    #pragma unroll
    for (int t16 = 0; t16 < 4; ++t16) {
      bf16x8 pb  = *(const bf16x8*)(pstrip + swz_chunk(qL, t16 * 2 + hi));
      bf16x8 va0 = *(const bf16x8*)(vbase + swz_chunk(qL, t16 * 2 + hi));
      bf16x8 va1 = *(const bf16x8*)(vbase + swz_chunk(32 + qL, t16 * 2 + hi));
      o0 = mfma32(va0, pb, o0);
      o1 = mfma32(va1, pb, o1);
    }
    __syncthreads();
  }

  // ---- merge parity partners via LDS ----
  float* mlb = (float*)smem;           // [8 waves][32 q][2]
  if (hi == 0) {
    mlb[(wv * 32 + qL) * 2]     = m_r;
    mlb[(wv * 32 + qL) * 2 + 1] = l_r;
  }
  __syncthreads();
  float m_p = mlb[((wv ^ 1) * 32 + qL) * 2];
  float l_p = mlb[((wv ^ 1) * 32 + qL) * 2 + 1];
  float M = fmaxf(m_r, m_p);
  float w_s = __builtin_amdgcn_exp2f(m_r - M);
  float l_tot = l_r * w_s + l_p * __builtin_amdgcn_exp2f(m_p - M);
  char* obuf = smem + 2048 + wq * 8192;   // per-pair scratch, swizzled per-lane
  if (par == 0) {
    #pragma unroll
    for (int g = 0; g < 8; ++g) {
      f32x4 t;
      #pragma unroll
      for (int j = 0; j < 4; ++j)
        t[j] = (g < 4 ? o0[g * 4 + j] : o1[(g - 4) * 4 + j]) * w_s;
      *(f32x4*)(obuf + swz_chunk(lane, g)) = t;
    }
  }
  __syncthreads();
  if (par == 1) {
    float inv = 1.f / l_tot;
    int qglob = q0 + wq * 32 + qL;
    int b_ = bh >> 2, h = bh & 3;
    bf16_t* ab = aout + ((size_t)b_ * N + qglob) * C + h * HD;
    #pragma unroll
    for (int g = 0; g < 8; ++g) {
      f32x4 part = *(const f32x4*)(obuf + swz_chunk(lane, g));
      int hdb = g >> 2, gg = g & 3;
      bf16x4v ov;
      #pragma unroll
      for (int j = 0; j < 4; ++j) {
        float own = hdb ? o1[gg * 4 + j] : o0[gg * 4 + j];
        ov[j] = (bf16_t)((part[j] + own * w_s) * inv);
      }
      *(bf16x4v*)(ab + hdb * 32 + gg * 8 + hi * 4) = ov;
    }
  }
}

// ---------------------------------------------------------------------------
// Kernel 5: proj GEMM + bias + residual, writes [B,C,H,W] fp32 with float4
// ---------------------------------------------------------------------------
__global__ __launch_bounds__(256, 4) void gemm_proj(
    const bf16_t* __restrict__ aout, const bf16_t* __restrict__ wT,
    const float* __restrict__ bias, const float* __restrict__ x,
    float* __restrict__ out) {
  __shared__ char smem[2 * 8192];
  char* As = smem;
  char* Bs = smem + 8192;
  int tid = threadIdx.x, lane = tid & 63, wv = tid >> 6;
  int mt = blockIdx.x & 255, nt = blockIdx.x >> 8;   // 256 x 4
  int m0 = mt * 64, c0 = nt * 64;
  f32x4 acc[4];
  #pragma unroll
  for (int i = 0; i < 4; ++i) acc[i] = (f32x4){0.f, 0.f, 0.f, 0.f};
  for (int kt = 0; kt < 4; ++kt) {
    int k0 = kt * 64;
    __syncthreads();
    #pragma unroll
    for (int it = 0; it < 2; ++it) {
      int idx = it * 256 + tid, row = idx >> 3, cb = idx & 7;
      *(i32x4*)(As + swz_chunk(row, cb)) =
          *(const i32x4*)(aout + (size_t)(m0 + row) * C + k0 + cb * 8);
      *(i32x4*)(Bs + swz_chunk(row, cb)) =
          *(const i32x4*)(wT + (size_t)(c0 + row) * C + k0 + cb * 8);
    }
    __syncthreads();
    int r = wv * 16 + (lane & 15), q = lane >> 4;
    bf16x8 a0 = *(const bf16x8*)(As + swz_chunk(r, q));
    bf16x8 a1 = *(const bf16x8*)(As + swz_chunk(r, 4 + q));
    #pragma unroll
    for (int ct = 0; ct < 4; ++ct) {
      int br = ct * 16 + (lane & 15);
      bf16x8 b0 = *(const bf16x8*)(Bs + swz_chunk(br, q));
      bf16x8 b1 = *(const bf16x8*)(Bs + swz_chunk(br, 4 + q));
      acc[ct] = mfma16(a0, b0, acc[ct]);
      acc[ct] = mfma16(a1, b1, acc[ct]);
    }
  }
  #pragma unroll
  for (int ct = 0; ct < 4; ++ct) {
    int c = c0 + ct * 16 + (lane & 15);
    float bv = bias[c];
    int m = m0 + wv * 16 + (lane >> 4) * 4;   // 4 consecutive tokens
    int b_ = m >> 12, n = m & 4095;
    size_t off = ((size_t)(b_ * C + c)) * N + n;
    f32x4 xin = *(const f32x4*)(x + off);
    f32x4 res;
    #pragma unroll
    for (int j = 0; j < 4; ++j) res[j] = xin[j] + acc[ct][j] + bv;
    *(f32x4*)(out + off) = res;
  }
}

// ---------------------------------------------------------------------------
extern "C" void kernel_launch(void* const* d_in, const int* in_sizes, int n_in,
                              void* d_out, int out_size, void* d_ws, size_t ws_size,
                              hipStream_t stream) {
  const float* x     = (const float*)d_in[0];
  const float* gam   = (const float*)d_in[1];
  const float* bet   = (const float*)d_in[2];
  const float* wqkv  = (const float*)d_in[3];
  const float* bqkv  = (const float*)d_in[4];
  const float* wproj = (const float*)d_in[5];
  const float* bproj = (const float*)d_in[6];
  float* out = (float*)d_out;

  char* ws = (char*)d_ws;
  size_t off = 0;
  auto alloc = [&](size_t bytes) {
    void* p = ws + off;
    off += (bytes + 255) & ~(size_t)255;
    return p;
  };
  bf16_t* xn     = (bf16_t*)alloc((size_t)Bb * N * C * 2);
  bf16_t* wqkvT  = (bf16_t*)alloc((size_t)768 * 256 * 2);
  bf16_t* wprojT = (bf16_t*)alloc((size_t)256 * 256 * 2);
  bf16_t* Qb     = (bf16_t*)alloc((size_t)Bb * NH * N * HD * 2);
  bf16_t* Kb     = (bf16_t*)alloc((size_t)Bb * NH * N * HD * 2);
  bf16_t* Vtb    = (bf16_t*)alloc((size_t)Bb * NH * HD * N * 2);
  bf16_t* aout   = (bf16_t*)alloc((size_t)Bb * N * C * 2);
  if (ws_size < off) return;   // workspace too small: fail loudly via poisoned out

  hipLaunchKernelGGL(ln_kernel, dim3(Bb * 64), dim3(256), 0, stream, x, gam, bet, xn);
  hipLaunchKernelGGL(conv_w, dim3(768), dim3(256), 0, stream, wqkv, wproj, wqkvT, wprojT);
  hipLaunchKernelGGL(gemm_qkv, dim3(256 * 12), dim3(256), 0, stream, xn, wqkvT, bqkv,
                     Qb, Kb, Vtb);
  hipLaunchKernelGGL(attn_kernel, dim3(16 * 32), dim3(512), 0, stream,
                     Qb, Kb, Vtb, aout);
  hipLaunchKernelGGL(gemm_proj, dim3(256 * 4), dim3(256), 0, stream, aout, wprojT,
                     bproj, x, out);
}

// Round 7
// 208.554 us; speedup vs baseline: 1.5622x; 1.0300x over previous
//
#include <hip/hip_runtime.h>
#include <hip/hip_bf16.h>

typedef __bf16 bf16_t;
typedef bf16_t bf16x8 __attribute__((ext_vector_type(8)));
typedef bf16_t bf16x4v __attribute__((ext_vector_type(4)));
typedef float f32x4 __attribute__((ext_vector_type(4)));
typedef float f32x16 __attribute__((ext_vector_type(16)));
typedef int i32x4 __attribute__((ext_vector_type(4)));
typedef int i32x2 __attribute__((ext_vector_type(2)));

constexpr int C = 256;
constexpr int Bb = 4;
constexpr int N = 4096;   // 64*64 tokens per batch
constexpr int NH = 4;
constexpr int HD = 64;
// fold (1/sqrt(C)) * log2(e) into Q so softmax uses exp2 directly
constexpr float SM_SCALE_LOG2E = 0.0625f * 1.44269504088896340736f;

// byte offset of 16B chunk `chunk` in row `row` of a [rows][64 bf16] LDS tile,
// XOR-swizzled to kill the 128B-row-stride bank conflict (guide G4 / T2)
__device__ __forceinline__ int swz_chunk(int row, int chunk) {
  return row * 128 + ((chunk ^ (row & 7)) << 4);
}

__device__ __forceinline__ f32x4 mfma16(bf16x8 a, bf16x8 b, f32x4 c) {
  return __builtin_amdgcn_mfma_f32_16x16x32_bf16(a, b, c, 0, 0, 0);
}
__device__ __forceinline__ f32x16 mfma32(bf16x8 a, bf16x8 b, f32x16 c) {
  return __builtin_amdgcn_mfma_f32_32x32x16_bf16(a, b, c, 0, 0, 0);
}

// pack two f32 into one dword of 2 bf16 (src0 -> low 16 bits)
__device__ __forceinline__ int cvt_pk_bf16(float lo, float hi) {
  int d;
  asm("v_cvt_pk_bf16_f32 %0, %1, %2" : "=v"(d) : "v"(lo), "v"(hi));
  return d;
}
// v_permlane32_swap_b32: r[0] = {X.lo | Y.lo}, r[1] = {X.hi | Y.hi}
// (X's high 32 lanes exchanged with Y's low 32 lanes)
__device__ __forceinline__ i32x2 plswap(int a, int b) {
  return __builtin_amdgcn_permlane32_swap(a, b, false, false);
}
// reduce with lane^32 partner without DS-pipe shuffles
__device__ __forceinline__ float xhalf_max(float v) {
  i32x2 r = plswap(__float_as_int(v), __float_as_int(v));
  return fmaxf(__int_as_float(r[0]), __int_as_float(r[1]));
}
__device__ __forceinline__ float xhalf_sum(float v) {
  i32x2 r = plswap(__float_as_int(v), __float_as_int(v));
  return __int_as_float(r[0]) + __int_as_float(r[1]);
}

// ---------------------------------------------------------------------------
// Kernel 1: LayerNorm over C with [B,C,N] -> [B,N,C] transpose, bf16 out
// ---------------------------------------------------------------------------
__global__ __launch_bounds__(256, 2) void ln_kernel(
    const float* __restrict__ x, const float* __restrict__ gamma,
    const float* __restrict__ beta, bf16_t* __restrict__ xn) {
  __shared__ float tile[256][65];       // [channel][token], padded
  __shared__ float red[2][4][64];
  __shared__ float mu_s[64], rs_s[64];
  int tid = threadIdx.x, lane = tid & 63, wv = tid >> 6;
  int b = blockIdx.x >> 6;
  int n0 = (blockIdx.x & 63) << 6;
  const float* xb = x + ((size_t)b * C) * N + n0;
  #pragma unroll 4
  for (int i = 0; i < 64; ++i) {
    int c = wv * 64 + i;
    tile[c][lane] = xb[(size_t)c * N + lane];   // coalesced along tokens
  }
  __syncthreads();
  // token = lane, channel-quarter = wv
  float s = 0.f, s2 = 0.f;
  #pragma unroll 8
  for (int i = 0; i < 64; ++i) {
    float v = tile[wv * 64 + i][lane];
    s += v; s2 += v * v;
  }
  red[0][wv][lane] = s; red[1][wv][lane] = s2;
  __syncthreads();
  if (tid < 64) {
    float ts  = red[0][0][tid] + red[0][1][tid] + red[0][2][tid] + red[0][3][tid];
    float ts2 = red[1][0][tid] + red[1][1][tid] + red[1][2][tid] + red[1][3][tid];
    float mu  = ts * (1.f / 256.f);
    float var = fmaxf(ts2 * (1.f / 256.f) - mu * mu, 0.f);
    mu_s[tid] = mu;
    rs_s[tid] = rsqrtf(var + 1e-5f);
  }
  __syncthreads();
  float g = gamma[tid], be = beta[tid];
  bf16_t* xo = xn + ((size_t)(b * N + n0)) * C + tid;
  #pragma unroll 4
  for (int i = 0; i < 64; ++i) {
    float v = (tile[tid][i] - mu_s[i]) * rs_s[i] * g + be;
    xo[(size_t)i * C] = (bf16_t)v;     // coalesced along channels
  }
}

// ---------------------------------------------------------------------------
// Kernel 2: weights -> bf16, transposed to B^T layout [ncol][k]
// ---------------------------------------------------------------------------
__global__ void conv_w(const float* __restrict__ wqkv, const float* __restrict__ wproj,
                       bf16_t* __restrict__ wqkvT, bf16_t* __restrict__ wprojT) {
  int id = blockIdx.x * 256 + threadIdx.x;
  if (id < 768 * 256) {
    int nn = id >> 8, kk = id & 255;
    wqkvT[id] = (bf16_t)wqkv[(size_t)kk * 768 + nn];
  }
  if (id < 256 * 256) {
    int nn = id >> 8, kk = id & 255;
    wprojT[id] = (bf16_t)wproj[(size_t)kk * 256 + nn];
  }
}

// ---------------------------------------------------------------------------
// Kernel 3: QKV GEMM  xn[16384,256] @ w[256,768] + b  -> Q (scaled), K, Vt
// ---------------------------------------------------------------------------
__global__ __launch_bounds__(256, 4) void gemm_qkv(
    const bf16_t* __restrict__ xn, const bf16_t* __restrict__ wT,
    const float* __restrict__ bias,
    bf16_t* __restrict__ Q, bf16_t* __restrict__ K, bf16_t* __restrict__ Vt) {
  __shared__ char smem[2 * 8192];
  char* As = smem;            // [64 m][64 k] bf16 swizzled
  char* Bs = smem + 8192;     // [64 n][64 k]
  int tid = threadIdx.x, lane = tid & 63, wv = tid >> 6;
  int mt = blockIdx.x & 255, nt = blockIdx.x >> 8;   // 256 x 12
  int m0 = mt * 64, ncol0 = nt * 64;
  f32x4 acc[4];
  #pragma unroll
  for (int i = 0; i < 4; ++i) acc[i] = (f32x4){0.f, 0.f, 0.f, 0.f};
  for (int kt = 0; kt < 4; ++kt) {
    int k0 = kt * 64;
    __syncthreads();
    #pragma unroll
    for (int it = 0; it < 2; ++it) {
      int idx = it * 256 + tid, row = idx >> 3, cb = idx & 7;
      *(i32x4*)(As + swz_chunk(row, cb)) =
          *(const i32x4*)(xn + (size_t)(m0 + row) * C + k0 + cb * 8);
      *(i32x4*)(Bs + swz_chunk(row, cb)) =
          *(const i32x4*)(wT + (size_t)(ncol0 + row) * C + k0 + cb * 8);
    }
    __syncthreads();
    int r = wv * 16 + (lane & 15), q = lane >> 4;
    bf16x8 a0 = *(const bf16x8*)(As + swz_chunk(r, q));
    bf16x8 a1 = *(const bf16x8*)(As + swz_chunk(r, 4 + q));
    #pragma unroll
    for (int ct = 0; ct < 4; ++ct) {
      int br = ct * 16 + (lane & 15);
      bf16x8 b0 = *(const bf16x8*)(Bs + swz_chunk(br, q));
      bf16x8 b1 = *(const bf16x8*)(Bs + swz_chunk(br, 4 + q));
      acc[ct] = mfma16(a0, b0, acc[ct]);
      acc[ct] = mfma16(a1, b1, acc[ct]);
    }
  }
  #pragma unroll
  for (int ct = 0; ct < 4; ++ct) {
    int cg = ncol0 + ct * 16 + (lane & 15);
    float bv = bias[cg];
    int sect = cg >> 8;          // 0=q, 1=k, 2=v
    int cc = cg & 255;
    int h = cc >> 6, d = cc & 63;
    #pragma unroll
    for (int j = 0; j < 4; ++j) {
      int m = m0 + wv * 16 + (lane >> 4) * 4 + j;
      int b_ = m >> 12, n = m & 4095;
      float v = acc[ct][j] + bv;
      if (sect == 0) {
        Q[((size_t)((b_ * NH + h) * N + n)) * HD + d] = (bf16_t)(v * SM_SCALE_LOG2E);
      } else if (sect == 1) {
        K[((size_t)((b_ * NH + h) * N + n)) * HD + d] = (bf16_t)v;
      } else {
        Vt[((size_t)((b_ * NH + h) * HD + d)) * N + n] = (bf16_t)v;  // V transposed
      }
    }
  }
}

// ---------------------------------------------------------------------------
// Kernel 4: flash attention v4b — 32x32x16 MFMA, swapped operands,
// T14 pipelined staging, T12 P-in-registers (corrected permlane assembly).
// 512 threads = 8 waves = 4 q-groups x 2 k-parities; QBLK=128.
// ---------------------------------------------------------------------------
__global__ __launch_bounds__(512, 4) void attn_kernel(
    const bf16_t* __restrict__ Q, const bf16_t* __restrict__ K,
    const bf16_t* __restrict__ Vt, bf16_t* __restrict__ aout) {
  __shared__ char smem[34816];
  // [0,32K): K-even | V-even | K-odd | V-odd (8KB each); Q tile overlays
  // [0,16K) at start; merge obuf overlays [0,32K) at end. [32K,34K): m/l.
  char* tiles = smem;
  int tid = threadIdx.x, lane = tid & 63, wv = tid >> 6;
  int hi = lane >> 5, qL = lane & 31;
  int wq = wv >> 1, par = wv & 1;
  int bh = blockIdx.x >> 5, qt = blockIdx.x & 31;
  int q0 = qt * 128;

  const bf16_t* Kbh = K + (size_t)bh * N * HD;
  const bf16_t* Vbh = Vt + (size_t)bh * HD * N;
  int srow = tid >> 3, scb = tid & 7;  // staging coords: 64B/thread/tile
  int sd = swz_chunk(srow, scb);

  // T14 prologue: issue K/V loads for advance 0 (consumed at first ds_write)
  i32x4 st0 = *(const i32x4*)(Kbh + (size_t)srow * HD + scb * 8);
  i32x4 st1 = *(const i32x4*)(Vbh + (size_t)srow * N + scb * 8);
  i32x4 st2 = *(const i32x4*)(Kbh + (size_t)(64 + srow) * HD + scb * 8);
  i32x4 st3 = *(const i32x4*)(Vbh + (size_t)srow * N + 64 + scb * 8);

  // stage Q tile (128 q x 64 hd) into tiles[0,16K)
  const bf16_t* Qbase = Q + ((size_t)bh * N + q0) * HD;
  #pragma unroll
  for (int it = 0; it < 2; ++it) {
    int idx = it * 512 + tid;          // 1024 chunks of 16B
    int row = idx >> 3, cb = idx & 7;
    *(i32x4*)(tiles + swz_chunk(row, cb)) =
        *(const i32x4*)(Qbase + (size_t)row * HD + cb * 8);
  }
  __syncthreads();
  // Q b-frags: row = wq*32+qL, k-slice hd = hs*16 + hi*8 + i
  bf16x8 qb[4];
  #pragma unroll
  for (int hs = 0; hs < 4; ++hs)
    qb[hs] = *(const bf16x8*)(tiles + swz_chunk(wq * 32 + qL, hs * 2 + hi));
  __syncthreads();   // all Q reads drained before tiles is overwritten

  char* kbase = tiles + par * 16384;
  char* vbase = kbase + 8192;

  float m_r = -3.0e38f, l_r = 0.f;     // per-lane stats for q = q0+wq*32+qL
  f32x16 o0, o1;                       // O^T: hd = hdb*32 + (r&3)+8*(r>>2)+4*hi
  #pragma unroll
  for (int i = 0; i < 16; ++i) { o0[i] = 0.f; o1[i] = 0.f; }

  for (int adv = 0; adv < 32; ++adv) {
    // write staged regs (vmcnt waited here), publish
    *(i32x4*)(tiles + sd)         = st0;
    *(i32x4*)(tiles + 8192 + sd)  = st1;
    *(i32x4*)(tiles + 16384 + sd) = st2;
    *(i32x4*)(tiles + 24576 + sd) = st3;
    __syncthreads();
    // issue next advance's loads; latency hides under this iter's compute
    if (adv < 31) {
      int n1 = (adv + 1) * 128;
      st0 = *(const i32x4*)(Kbh + (size_t)(n1 + srow) * HD + scb * 8);
      st1 = *(const i32x4*)(Vbh + (size_t)srow * N + n1 + scb * 8);
      st2 = *(const i32x4*)(Kbh + (size_t)(n1 + 64 + srow) * HD + scb * 8);
      st3 = *(const i32x4*)(Vbh + (size_t)srow * N + n1 + 64 + scb * 8);
    }
    // S^T = K(64 tok) x Q(32 q): s0 = tokens 0-31 of this parity's tile
    f32x16 s0, s1;
    #pragma unroll
    for (int i = 0; i < 16; ++i) { s0[i] = 0.f; s1[i] = 0.f; }
    #pragma unroll
    for (int hs = 0; hs < 4; ++hs) {
      bf16x8 ka0 = *(const bf16x8*)(kbase + swz_chunk(qL, hs * 2 + hi));
      bf16x8 ka1 = *(const bf16x8*)(kbase + swz_chunk(32 + qL, hs * 2 + hi));
      s0 = mfma32(ka0, qb[hs], s0);
      s1 = mfma32(ka1, qb[hs], s1);
    }
    // online softmax: 32 lane-local values + 1 permlane half-exchange
    float tm = s0[0];
    #pragma unroll
    for (int i = 1; i < 16; ++i) tm = fmaxf(tm, s0[i]);
    #pragma unroll
    for (int i = 0; i < 16; ++i) tm = fmaxf(tm, s1[i]);
    tm = xhalf_max(tm);
    float nm = fmaxf(m_r, tm);
    if (!__all(nm == m_r)) {           // exact defer: rescale only on growth
      float f = __builtin_amdgcn_exp2f(m_r - nm);
      l_r *= f;
      o0 *= f; o1 *= f;
      m_r = nm;
    }
    float rs = 0.f;
    #pragma unroll
    for (int i = 0; i < 16; ++i) {
      float p = __builtin_amdgcn_exp2f(s0[i] - m_r); s0[i] = p; rs += p;
    }
    #pragma unroll
    for (int i = 0; i < 16; ++i) {
      float p = __builtin_amdgcn_exp2f(s1[i] - m_r); s1[i] = p; rs += p;
    }
    l_r += xhalf_sum(rs);
    // P-frags in registers. Lane (hi,qL) holds tokens 8g+4hi+{0..3} (g=0..3
    // per 32-token half). B-frag(t16) needs tokens 16t16+8hi+{0..7}:
    //   w0=(+0,+1) w1=(+2,+3) w2=(+4,+5) w3=(+6,+7).
    // With rA = plswap(dE0,dO0) (X.hi<->Y.lo):
    //   rA[0] = {dE0.lo | dO0.lo} = w0  (hi0: own (0,1); hi1: partner (8,9))
    //   rA[1] = {dE0.hi | dO0.hi} = w2  (hi0: partner (4,5); hi1: own (12,13))
    #pragma unroll
    for (int t16 = 0; t16 < 4; ++t16) {
      int dE0, dE1, dO0, dO1;
      if (t16 < 2) {
        dE0 = cvt_pk_bf16(s0[t16 * 8 + 0], s0[t16 * 8 + 1]);
        dE1 = cvt_pk_bf16(s0[t16 * 8 + 2], s0[t16 * 8 + 3]);
        dO0 = cvt_pk_bf16(s0[t16 * 8 + 4], s0[t16 * 8 + 5]);
        dO1 = cvt_pk_bf16(s0[t16 * 8 + 6], s0[t16 * 8 + 7]);
      } else {
        dE0 = cvt_pk_bf16(s1[(t16 - 2) * 8 + 0], s1[(t16 - 2) * 8 + 1]);
        dE1 = cvt_pk_bf16(s1[(t16 - 2) * 8 + 2], s1[(t16 - 2) * 8 + 3]);
        dO0 = cvt_pk_bf16(s1[(t16 - 2) * 8 + 4], s1[(t16 - 2) * 8 + 5]);
        dO1 = cvt_pk_bf16(s1[(t16 - 2) * 8 + 6], s1[(t16 - 2) * 8 + 7]);
      }
      i32x2 rA = plswap(dE0, dO0);
      i32x2 rB = plswap(dE1, dO1);
      union { i32x4 i; bf16x8 h; } u;
      u.i = (i32x4){rA[0], rB[0], rA[1], rB[1]};
      bf16x8 va0 = *(const bf16x8*)(vbase + swz_chunk(qL, t16 * 2 + hi));
      bf16x8 va1 = *(const bf16x8*)(vbase + swz_chunk(32 + qL, t16 * 2 + hi));
      o0 = mfma32(va0, u.h, o0);
      o1 = mfma32(va1, u.h, o1);
    }
    __syncthreads();   // all reads of tiles done; next iter overwrites
  }

  // ---- merge parity partners via LDS ----
  float* mlb = (float*)(smem + 32768);   // [8 waves][32 q][2]
  if (hi == 0) {
    mlb[(wv * 32 + qL) * 2]     = m_r;
    mlb[(wv * 32 + qL) * 2 + 1] = l_r;
  }
  __syncthreads();
  float m_p = mlb[((wv ^ 1) * 32 + qL) * 2];
  float l_p = mlb[((wv ^ 1) * 32 + qL) * 2 + 1];
  float M = fmaxf(m_r, m_p);
  float w_s = __builtin_amdgcn_exp2f(m_r - M);
  float l_tot = l_r * w_s + l_p * __builtin_amdgcn_exp2f(m_p - M);
  char* obuf = smem + wq * 8192;         // per-pair scratch over tiles region
  if (par == 0) {
    #pragma unroll
    for (int g = 0; g < 8; ++g) {
      f32x4 t;
      #pragma unroll
      for (int j = 0; j < 4; ++j)
        t[j] = (g < 4 ? o0[g * 4 + j] : o1[(g - 4) * 4 + j]) * w_s;
      *(f32x4*)(obuf + swz_chunk(lane, g)) = t;
    }
  }
  __syncthreads();
  if (par == 1) {
    float inv = 1.f / l_tot;
    int qglob = q0 + wq * 32 + qL;
    int b_ = bh >> 2, h = bh & 3;
    bf16_t* ab = aout + ((size_t)b_ * N + qglob) * C + h * HD;
    #pragma unroll
    for (int g = 0; g < 8; ++g) {
      f32x4 part = *(const f32x4*)(obuf + swz_chunk(lane, g));
      int hdb = g >> 2, gg = g & 3;
      bf16x4v ov;
      #pragma unroll
      for (int j = 0; j < 4; ++j) {
        float own = hdb ? o1[gg * 4 + j] : o0[gg * 4 + j];
        ov[j] = (bf16_t)((part[j] + own * w_s) * inv);
      }
      *(bf16x4v*)(ab + hdb * 32 + gg * 8 + hi * 4) = ov;
    }
  }
}

// ---------------------------------------------------------------------------
// Kernel 5: proj GEMM + bias + residual, writes [B,C,H,W] fp32 with float4
// ---------------------------------------------------------------------------
__global__ __launch_bounds__(256, 4) void gemm_proj(
    const bf16_t* __restrict__ aout, const bf16_t* __restrict__ wT,
    const float* __restrict__ bias, const float* __restrict__ x,
    float* __restrict__ out) {
  __shared__ char smem[2 * 8192];
  char* As = smem;
  char* Bs = smem + 8192;
  int tid = threadIdx.x, lane = tid & 63, wv = tid >> 6;
  int mt = blockIdx.x & 255, nt = blockIdx.x >> 8;   // 256 x 4
  int m0 = mt * 64, c0 = nt * 64;
  f32x4 acc[4];
  #pragma unroll
  for (int i = 0; i < 4; ++i) acc[i] = (f32x4){0.f, 0.f, 0.f, 0.f};
  for (int kt = 0; kt < 4; ++kt) {
    int k0 = kt * 64;
    __syncthreads();
    #pragma unroll
    for (int it = 0; it < 2; ++it) {
      int idx = it * 256 + tid, row = idx >> 3, cb = idx & 7;
      *(i32x4*)(As + swz_chunk(row, cb)) =
          *(const i32x4*)(aout + (size_t)(m0 + row) * C + k0 + cb * 8);
      *(i32x4*)(Bs + swz_chunk(row, cb)) =
          *(const i32x4*)(wT + (size_t)(c0 + row) * C + k0 + cb * 8);
    }
    __syncthreads();
    int r = wv * 16 + (lane & 15), q = lane >> 4;
    bf16x8 a0 = *(const bf16x8*)(As + swz_chunk(r, q));
    bf16x8 a1 = *(const bf16x8*)(As + swz_chunk(r, 4 + q));
    #pragma unroll
    for (int ct = 0; ct < 4; ++ct) {
      int br = ct * 16 + (lane & 15);
      bf16x8 b0 = *(const bf16x8*)(Bs + swz_chunk(br, q));
      bf16x8 b1 = *(const bf16x8*)(Bs + swz_chunk(br, 4 + q));
      acc[ct] = mfma16(a0, b0, acc[ct]);
      acc[ct] = mfma16(a1, b1, acc[ct]);
    }
  }
  #pragma unroll
  for (int ct = 0; ct < 4; ++ct) {
    int c = c0 + ct * 16 + (lane & 15);
    float bv = bias[c];
    int m = m0 + wv * 16 + (lane >> 4) * 4;   // 4 consecutive tokens
    int b_ = m >> 12, n = m & 4095;
    size_t off = ((size_t)(b_ * C + c)) * N + n;
    f32x4 xin = *(const f32x4*)(x + off);
    f32x4 res;
    #pragma unroll
    for (int j = 0; j < 4; ++j) res[j] = xin[j] + acc[ct][j] + bv;
    *(f32x4*)(out + off) = res;
  }
}

// ---------------------------------------------------------------------------
extern "C" void kernel_launch(void* const* d_in, const int* in_sizes, int n_in,
                              void* d_out, int out_size, void* d_ws, size_t ws_size,
                              hipStream_t stream) {
  const float* x     = (const float*)d_in[0];
  const float* gam   = (const float*)d_in[1];
  const float* bet   = (const float*)d_in[2];
  const float* wqkv  = (const float*)d_in[3];
  const float* bqkv  = (const float*)d_in[4];
  const float* wproj = (const float*)d_in[5];
  const float* bproj = (const float*)d_in[6];
  float* out = (float*)d_out;

  char* ws = (char*)d_ws;
  size_t off = 0;
  auto alloc = [&](size_t bytes) {
    void* p = ws + off;
    off += (bytes + 255) & ~(size_t)255;
    return p;
  };
  bf16_t* xn     = (bf16_t*)alloc((size_t)Bb * N * C * 2);
  bf16_t* wqkvT  = (bf16_t*)alloc((size_t)768 * 256 * 2);
  bf16_t* wprojT = (bf16_t*)alloc((size_t)256 * 256 * 2);
  bf16_t* Qb     = (bf16_t*)alloc((size_t)Bb * NH * N * HD * 2);
  bf16_t* Kb     = (bf16_t*)alloc((size_t)Bb * NH * N * HD * 2);
  bf16_t* Vtb    = (bf16_t*)alloc((size_t)Bb * NH * HD * N * 2);
  bf16_t* aout   = (bf16_t*)alloc((size_t)Bb * N * C * 2);
  if (ws_size < off) return;   // workspace too small: fail loudly via poisoned out

  hipLaunchKernelGGL(ln_kernel, dim3(Bb * 64), dim3(256), 0, stream, x, gam, bet, xn);
  hipLaunchKernelGGL(conv_w, dim3(768), dim3(256), 0, stream, wqkv, wproj, wqkvT, wprojT);
  hipLaunchKernelGGL(gemm_qkv, dim3(256 * 12), dim3(256), 0, stream, xn, wqkvT, bqkv,
                     Qb, Kb, Vtb);
  hipLaunchKernelGGL(attn_kernel, dim3(16 * 32), dim3(512), 0, stream,
                     Qb, Kb, Vtb, aout);
  hipLaunchKernelGGL(gemm_proj, dim3(256 * 4), dim3(256), 0, stream, aout, wprojT,
                     bproj, x, out);
}

// Round 8
// 198.736 us; speedup vs baseline: 1.6394x; 1.0494x over previous
//
#include <hip/hip_runtime.h>
#include <hip/hip_bf16.h>

typedef __bf16 bf16_t;
typedef bf16_t bf16x8 __attribute__((ext_vector_type(8)));
typedef bf16_t bf16x4v __attribute__((ext_vector_type(4)));
typedef float f32x4 __attribute__((ext_vector_type(4)));
typedef float f32x16 __attribute__((ext_vector_type(16)));
typedef int i32x4 __attribute__((ext_vector_type(4)));
typedef int i32x2 __attribute__((ext_vector_type(2)));

constexpr int C = 256;
constexpr int Bb = 4;
constexpr int N = 4096;   // 64*64 tokens per batch
constexpr int NH = 4;
constexpr int HD = 64;
// fold (1/sqrt(C)) * log2(e) into Q so softmax uses exp2 directly
constexpr float SM_SCALE_LOG2E = 0.0625f * 1.44269504088896340736f;

// byte offset of 16B chunk `chunk` in row `row` of a [rows][64 bf16] LDS tile,
// XOR-swizzled to kill the 128B-row-stride bank conflict (guide G4 / T2)
__device__ __forceinline__ int swz_chunk(int row, int chunk) {
  return row * 128 + ((chunk ^ (row & 7)) << 4);
}

__device__ __forceinline__ f32x4 mfma16(bf16x8 a, bf16x8 b, f32x4 c) {
  return __builtin_amdgcn_mfma_f32_16x16x32_bf16(a, b, c, 0, 0, 0);
}
__device__ __forceinline__ f32x16 mfma32(bf16x8 a, bf16x8 b, f32x16 c) {
  return __builtin_amdgcn_mfma_f32_32x32x16_bf16(a, b, c, 0, 0, 0);
}

// async global->LDS, 16B per lane; LDS dest must be wave-uniform base + lane*16
__device__ __forceinline__ void glds16(const void* g, void* l) {
  __builtin_amdgcn_global_load_lds(
      (const __attribute__((address_space(1))) void*)g,
      (__attribute__((address_space(3))) void*)l, 16, 0, 0);
}

// pack two f32 into one dword of 2 bf16 (src0 -> low 16 bits)
__device__ __forceinline__ int cvt_pk_bf16(float lo, float hi) {
  int d;
  asm("v_cvt_pk_bf16_f32 %0, %1, %2" : "=v"(d) : "v"(lo), "v"(hi));
  return d;
}
// v_permlane32_swap_b32: r[0] = {X.lo | Y.lo}, r[1] = {X.hi | Y.hi}
__device__ __forceinline__ i32x2 plswap(int a, int b) {
  return __builtin_amdgcn_permlane32_swap(a, b, false, false);
}
__device__ __forceinline__ float xhalf_max(float v) {
  i32x2 r = plswap(__float_as_int(v), __float_as_int(v));
  return fmaxf(__int_as_float(r[0]), __int_as_float(r[1]));
}
__device__ __forceinline__ float xhalf_sum(float v) {
  i32x2 r = plswap(__float_as_int(v), __float_as_int(v));
  return __int_as_float(r[0]) + __int_as_float(r[1]);
}

// ---------------------------------------------------------------------------
// Kernel 1: LayerNorm over C with [B,C,N] -> [B,N,C] transpose, bf16 out
// ---------------------------------------------------------------------------
__global__ __launch_bounds__(256, 2) void ln_kernel(
    const float* __restrict__ x, const float* __restrict__ gamma,
    const float* __restrict__ beta, bf16_t* __restrict__ xn) {
  __shared__ float tile[256][65];       // [channel][token], padded
  __shared__ float red[2][4][64];
  __shared__ float mu_s[64], rs_s[64];
  int tid = threadIdx.x, lane = tid & 63, wv = tid >> 6;
  int b = blockIdx.x >> 6;
  int n0 = (blockIdx.x & 63) << 6;
  const float* xb = x + ((size_t)b * C) * N + n0;
  #pragma unroll 4
  for (int i = 0; i < 64; ++i) {
    int c = wv * 64 + i;
    tile[c][lane] = xb[(size_t)c * N + lane];   // coalesced along tokens
  }
  __syncthreads();
  float s = 0.f, s2 = 0.f;
  #pragma unroll 8
  for (int i = 0; i < 64; ++i) {
    float v = tile[wv * 64 + i][lane];
    s += v; s2 += v * v;
  }
  red[0][wv][lane] = s; red[1][wv][lane] = s2;
  __syncthreads();
  if (tid < 64) {
    float ts  = red[0][0][tid] + red[0][1][tid] + red[0][2][tid] + red[0][3][tid];
    float ts2 = red[1][0][tid] + red[1][1][tid] + red[1][2][tid] + red[1][3][tid];
    float mu  = ts * (1.f / 256.f);
    float var = fmaxf(ts2 * (1.f / 256.f) - mu * mu, 0.f);
    mu_s[tid] = mu;
    rs_s[tid] = rsqrtf(var + 1e-5f);
  }
  __syncthreads();
  float g = gamma[tid], be = beta[tid];
  bf16_t* xo = xn + ((size_t)(b * N + n0)) * C + tid;
  #pragma unroll 4
  for (int i = 0; i < 64; ++i) {
    float v = (tile[tid][i] - mu_s[i]) * rs_s[i] * g + be;
    xo[(size_t)i * C] = (bf16_t)v;     // coalesced along channels
  }
}

// ---------------------------------------------------------------------------
// Kernel 2: weights -> bf16, transposed to B^T layout [ncol][k]
// ---------------------------------------------------------------------------
__global__ void conv_w(const float* __restrict__ wqkv, const float* __restrict__ wproj,
                       bf16_t* __restrict__ wqkvT, bf16_t* __restrict__ wprojT) {
  int id = blockIdx.x * 256 + threadIdx.x;
  if (id < 768 * 256) {
    int nn = id >> 8, kk = id & 255;
    wqkvT[id] = (bf16_t)wqkv[(size_t)kk * 768 + nn];
  }
  if (id < 256 * 256) {
    int nn = id >> 8, kk = id & 255;
    wprojT[id] = (bf16_t)wproj[(size_t)kk * 256 + nn];
  }
}

// ---------------------------------------------------------------------------
// Kernel 3: QKV GEMM, 128x128 tile — xn[16384,256] @ w[256,768] + b
// 4 waves, each owns a 64x64 sub-tile (acc 4x4 f32x4).
// ---------------------------------------------------------------------------
__global__ __launch_bounds__(256, 2) void gemm_qkv(
    const bf16_t* __restrict__ xn, const bf16_t* __restrict__ wT,
    const float* __restrict__ bias,
    bf16_t* __restrict__ Q, bf16_t* __restrict__ K, bf16_t* __restrict__ Vt) {
  __shared__ char smem[32768];
  char* As = smem;            // [128 m][64 k] bf16 swizzled
  char* Bs = smem + 16384;    // [128 n][64 k]
  int tid = threadIdx.x, lane = tid & 63, wv = tid >> 6;
  int mt = blockIdx.x & 127, nt = blockIdx.x >> 7;   // 128 x 6
  int m0 = mt * 128, ncol0 = nt * 128;
  int wr = wv >> 1, wc = wv & 1;
  f32x4 acc[4][4];
  #pragma unroll
  for (int i = 0; i < 4; ++i)
    #pragma unroll
    for (int j = 0; j < 4; ++j) acc[i][j] = (f32x4){0.f, 0.f, 0.f, 0.f};
  int q = lane >> 4;
  for (int kt = 0; kt < 4; ++kt) {
    int k0 = kt * 64;
    __syncthreads();
    #pragma unroll
    for (int it = 0; it < 4; ++it) {
      int idx = it * 256 + tid, row = idx >> 3, cb = idx & 7;
      *(i32x4*)(As + swz_chunk(row, cb)) =
          *(const i32x4*)(xn + (size_t)(m0 + row) * C + k0 + cb * 8);
      *(i32x4*)(Bs + swz_chunk(row, cb)) =
          *(const i32x4*)(wT + (size_t)(ncol0 + row) * C + k0 + cb * 8);
    }
    __syncthreads();
    bf16x8 a[4][2];
    #pragma unroll
    for (int mi = 0; mi < 4; ++mi) {
      int ar = wr * 64 + mi * 16 + (lane & 15);
      a[mi][0] = *(const bf16x8*)(As + swz_chunk(ar, q));
      a[mi][1] = *(const bf16x8*)(As + swz_chunk(ar, 4 + q));
    }
    #pragma unroll
    for (int ci = 0; ci < 4; ++ci) {
      int br = wc * 64 + ci * 16 + (lane & 15);
      bf16x8 b0 = *(const bf16x8*)(Bs + swz_chunk(br, q));
      bf16x8 b1 = *(const bf16x8*)(Bs + swz_chunk(br, 4 + q));
      #pragma unroll
      for (int mi = 0; mi < 4; ++mi) {
        acc[mi][ci] = mfma16(a[mi][1], b1, mfma16(a[mi][0], b0, acc[mi][ci]));
      }
    }
  }
  #pragma unroll
  for (int ci = 0; ci < 4; ++ci) {
    int cg = ncol0 + wc * 64 + ci * 16 + (lane & 15);
    float bv = bias[cg];
    int sect = cg >> 8;          // 0=q, 1=k, 2=v
    int cc = cg & 255;
    int h = cc >> 6, d = cc & 63;
    #pragma unroll
    for (int mi = 0; mi < 4; ++mi) {
      #pragma unroll
      for (int j = 0; j < 4; ++j) {
        int m = m0 + wr * 64 + mi * 16 + (lane >> 4) * 4 + j;
        int b_ = m >> 12, n = m & 4095;
        float v = acc[mi][ci][j] + bv;
        if (sect == 0) {
          Q[((size_t)((b_ * NH + h) * N + n)) * HD + d] = (bf16_t)(v * SM_SCALE_LOG2E);
        } else if (sect == 1) {
          K[((size_t)((b_ * NH + h) * N + n)) * HD + d] = (bf16_t)v;
        } else {
          Vt[((size_t)((b_ * NH + h) * HD + d)) * N + n] = (bf16_t)v;
        }
      }
    }
  }
}

// ---------------------------------------------------------------------------
// Kernel 4: flash attention v5 — 32x32x16 MFMA, swapped operands,
// double-buffered global_load_lds staging (pre-swizzled global source,
// linear LDS dest), T12 P-in-registers, T13 defer-max (THR=8).
// 512 threads = 8 waves = 4 q-groups x 2 k-parities; QBLK=128.
// ---------------------------------------------------------------------------
__global__ __launch_bounds__(512, 4) void attn_kernel(
    const bf16_t* __restrict__ Q, const bf16_t* __restrict__ K,
    const bf16_t* __restrict__ Vt, bf16_t* __restrict__ aout) {
  __shared__ char smem[67584];
  // [0,32K) buf0: K-even|V-even|K-odd|V-odd (8KB each); [32K,64K) buf1.
  // Q tile overlays buf1 at start; merge obuf overlays buf0; [64K,66K) m/l.
  int tid = threadIdx.x, lane = tid & 63, wv = tid >> 6;
  int hi = lane >> 5, qL = lane & 31;
  int wq = wv >> 1, par = wv & 1;
  int bh = blockIdx.x >> 5, qt = blockIdx.x & 31;
  int q0 = qt * 128;

  const bf16_t* Kbh = K + (size_t)bh * N * HD;
  const bf16_t* Vbh = Vt + (size_t)bh * HD * N;
  // staging geometry: thread -> one 16B chunk per 8KB tile, LINEAR LDS dest
  // (tid*16); swizzle folded into the per-lane GLOBAL address (rule #21).
  int sr = tid >> 3;                    // row 0..63
  int sc = (tid & 7) ^ (sr & 7);        // logical chunk for this physical slot

  // issue advance-0 staging into buf0
  {
    char* lb = smem;
    glds16(Kbh + (size_t)sr * HD + sc * 8,            lb + tid * 16);
    glds16(Vbh + (size_t)sr * N + sc * 8,             lb + 8192 + tid * 16);
    glds16(Kbh + (size_t)(64 + sr) * HD + sc * 8,     lb + 16384 + tid * 16);
    glds16(Vbh + (size_t)sr * N + 64 + sc * 8,        lb + 24576 + tid * 16);
  }
  // stage Q tile (128 q x 64 hd) into buf1 region
  char* Qt = smem + 32768;
  const bf16_t* Qbase = Q + ((size_t)bh * N + q0) * HD;
  #pragma unroll
  for (int it = 0; it < 2; ++it) {
    int idx = it * 512 + tid;
    int row = idx >> 3, cb = idx & 7;
    *(i32x4*)(Qt + swz_chunk(row, cb)) =
        *(const i32x4*)(Qbase + (size_t)row * HD + cb * 8);
  }
  __syncthreads();
  bf16x8 qb[4];
  #pragma unroll
  for (int hs = 0; hs < 4; ++hs)
    qb[hs] = *(const bf16x8*)(Qt + swz_chunk(wq * 32 + qL, hs * 2 + hi));

  float m_r = -3.0e38f, l_r = 0.f;
  f32x16 o0, o1;
  #pragma unroll
  for (int i = 0; i < 16; ++i) { o0[i] = 0.f; o1[i] = 0.f; }

  for (int adv = 0; adv < 32; ++adv) {
    // barrier auto-drains vmcnt (this adv's glds) + lgkmcnt (Q-frag reads)
    __syncthreads();
    if (adv < 31) {                     // prefetch next tile into other buffer
      int n1 = (adv + 1) * 128;
      char* lb = smem + (((adv + 1) & 1) << 15);
      glds16(Kbh + (size_t)(n1 + sr) * HD + sc * 8,        lb + tid * 16);
      glds16(Vbh + (size_t)sr * N + n1 + sc * 8,           lb + 8192 + tid * 16);
      glds16(Kbh + (size_t)(n1 + 64 + sr) * HD + sc * 8,   lb + 16384 + tid * 16);
      glds16(Vbh + (size_t)sr * N + n1 + 64 + sc * 8,      lb + 24576 + tid * 16);
    }
    char* kbase = smem + ((adv & 1) << 15) + par * 16384;
    char* vbase = kbase + 8192;
    // S^T = K(64 tok) x Q(32 q)
    f32x16 s0, s1;
    #pragma unroll
    for (int i = 0; i < 16; ++i) { s0[i] = 0.f; s1[i] = 0.f; }
    #pragma unroll
    for (int hs = 0; hs < 4; ++hs) {
      bf16x8 ka0 = *(const bf16x8*)(kbase + swz_chunk(qL, hs * 2 + hi));
      bf16x8 ka1 = *(const bf16x8*)(kbase + swz_chunk(32 + qL, hs * 2 + hi));
      s0 = mfma32(ka0, qb[hs], s0);
      s1 = mfma32(ka1, qb[hs], s1);
    }
    // tile max: max3-friendly tree over 32 lane-local values + pair exchange
    float q0m = fmaxf(fmaxf(s0[0], s0[1]), fmaxf(s0[2], s0[3]));
    float q1m = fmaxf(fmaxf(s0[4], s0[5]), fmaxf(s0[6], s0[7]));
    float q2m = fmaxf(fmaxf(s0[8], s0[9]), fmaxf(s0[10], s0[11]));
    float q3m = fmaxf(fmaxf(s0[12], s0[13]), fmaxf(s0[14], s0[15]));
    float q4m = fmaxf(fmaxf(s1[0], s1[1]), fmaxf(s1[2], s1[3]));
    float q5m = fmaxf(fmaxf(s1[4], s1[5]), fmaxf(s1[6], s1[7]));
    float q6m = fmaxf(fmaxf(s1[8], s1[9]), fmaxf(s1[10], s1[11]));
    float q7m = fmaxf(fmaxf(s1[12], s1[13]), fmaxf(s1[14], s1[15]));
    float tm = fmaxf(fmaxf(fmaxf(q0m, q1m), fmaxf(q2m, q3m)),
                     fmaxf(fmaxf(q4m, q5m), fmaxf(q6m, q7m)));
    tm = xhalf_max(tm);
    // T13: rescale only when max grows by >8 (log2 domain); P <= 2^8 is safe
    if (!__all(tm - m_r <= 8.f)) {
      float nm = fmaxf(m_r, tm);
      float f = __builtin_amdgcn_exp2f(m_r - nm);
      l_r *= f;
      o0 *= f; o1 *= f;
      m_r = nm;
    }
    float rs = 0.f;
    #pragma unroll
    for (int i = 0; i < 16; ++i) {
      float p = __builtin_amdgcn_exp2f(s0[i] - m_r); s0[i] = p; rs += p;
    }
    #pragma unroll
    for (int i = 0; i < 16; ++i) {
      float p = __builtin_amdgcn_exp2f(s1[i] - m_r); s1[i] = p; rs += p;
    }
    l_r += xhalf_sum(rs);
    // P-frags in registers (T12): lane holds tokens 8g+4hi+{0..3};
    // B-frag(t16) needs 16t16+8hi+{0..7}. rA = plswap(dE0,dO0):
    // rA[0] = {dE0.lo|dO0.lo} = w0, rA[1] = {dE0.hi|dO0.hi} = w2.
    #pragma unroll
    for (int t16 = 0; t16 < 4; ++t16) {
      int dE0, dE1, dO0, dO1;
      if (t16 < 2) {
        dE0 = cvt_pk_bf16(s0[t16 * 8 + 0], s0[t16 * 8 + 1]);
        dE1 = cvt_pk_bf16(s0[t16 * 8 + 2], s0[t16 * 8 + 3]);
        dO0 = cvt_pk_bf16(s0[t16 * 8 + 4], s0[t16 * 8 + 5]);
        dO1 = cvt_pk_bf16(s0[t16 * 8 + 6], s0[t16 * 8 + 7]);
      } else {
        dE0 = cvt_pk_bf16(s1[(t16 - 2) * 8 + 0], s1[(t16 - 2) * 8 + 1]);
        dE1 = cvt_pk_bf16(s1[(t16 - 2) * 8 + 2], s1[(t16 - 2) * 8 + 3]);
        dO0 = cvt_pk_bf16(s1[(t16 - 2) * 8 + 4], s1[(t16 - 2) * 8 + 5]);
        dO1 = cvt_pk_bf16(s1[(t16 - 2) * 8 + 6], s1[(t16 - 2) * 8 + 7]);
      }
      i32x2 rA = plswap(dE0, dO0);
      i32x2 rB = plswap(dE1, dO1);
      union { i32x4 i; bf16x8 h; } u;
      u.i = (i32x4){rA[0], rB[0], rA[1], rB[1]};
      bf16x8 va0 = *(const bf16x8*)(vbase + swz_chunk(qL, t16 * 2 + hi));
      bf16x8 va1 = *(const bf16x8*)(vbase + swz_chunk(32 + qL, t16 * 2 + hi));
      o0 = mfma32(va0, u.h, o0);
      o1 = mfma32(va1, u.h, o1);
    }
  }

  // ---- merge parity partners via LDS ----
  __syncthreads();
  float* mlb = (float*)(smem + 65536);   // [8 waves][32 q][2]
  if (hi == 0) {
    mlb[(wv * 32 + qL) * 2]     = m_r;
    mlb[(wv * 32 + qL) * 2 + 1] = l_r;
  }
  __syncthreads();
  float m_p = mlb[((wv ^ 1) * 32 + qL) * 2];
  float l_p = mlb[((wv ^ 1) * 32 + qL) * 2 + 1];
  float M = fmaxf(m_r, m_p);
  float w_s = __builtin_amdgcn_exp2f(m_r - M);
  float l_tot = l_r * w_s + l_p * __builtin_amdgcn_exp2f(m_p - M);
  char* obuf = smem + wq * 8192;         // per-pair scratch over buf0 region
  if (par == 0) {
    #pragma unroll
    for (int g = 0; g < 8; ++g) {
      f32x4 t;
      #pragma unroll
      for (int j = 0; j < 4; ++j)
        t[j] = (g < 4 ? o0[g * 4 + j] : o1[(g - 4) * 4 + j]) * w_s;
      *(f32x4*)(obuf + swz_chunk(lane, g)) = t;
    }
  }
  __syncthreads();
  if (par == 1) {
    float inv = 1.f / l_tot;
    int qglob = q0 + wq * 32 + qL;
    int b_ = bh >> 2, h = bh & 3;
    bf16_t* ab = aout + ((size_t)b_ * N + qglob) * C + h * HD;
    #pragma unroll
    for (int g = 0; g < 8; ++g) {
      f32x4 part = *(const f32x4*)(obuf + swz_chunk(lane, g));
      int hdb = g >> 2, gg = g & 3;
      bf16x4v ov;
      #pragma unroll
      for (int j = 0; j < 4; ++j) {
        float own = hdb ? o1[gg * 4 + j] : o0[gg * 4 + j];
        ov[j] = (bf16_t)((part[j] + own * w_s) * inv);
      }
      *(bf16x4v*)(ab + hdb * 32 + gg * 8 + hi * 4) = ov;
    }
  }
}

// ---------------------------------------------------------------------------
// Kernel 5: proj GEMM + bias + residual, writes [B,C,H,W] fp32 with float4
// ---------------------------------------------------------------------------
__global__ __launch_bounds__(256, 4) void gemm_proj(
    const bf16_t* __restrict__ aout, const bf16_t* __restrict__ wT,
    const float* __restrict__ bias, const float* __restrict__ x,
    float* __restrict__ out) {
  __shared__ char smem[2 * 8192];
  char* As = smem;
  char* Bs = smem + 8192;
  int tid = threadIdx.x, lane = tid & 63, wv = tid >> 6;
  int mt = blockIdx.x & 255, nt = blockIdx.x >> 8;   // 256 x 4
  int m0 = mt * 64, c0 = nt * 64;
  f32x4 acc[4];
  #pragma unroll
  for (int i = 0; i < 4; ++i) acc[i] = (f32x4){0.f, 0.f, 0.f, 0.f};
  for (int kt = 0; kt < 4; ++kt) {
    int k0 = kt * 64;
    __syncthreads();
    #pragma unroll
    for (int it = 0; it < 2; ++it) {
      int idx = it * 256 + tid, row = idx >> 3, cb = idx & 7;
      *(i32x4*)(As + swz_chunk(row, cb)) =
          *(const i32x4*)(aout + (size_t)(m0 + row) * C + k0 + cb * 8);
      *(i32x4*)(Bs + swz_chunk(row, cb)) =
          *(const i32x4*)(wT + (size_t)(c0 + row) * C + k0 + cb * 8);
    }
    __syncthreads();
    int r = wv * 16 + (lane & 15), q = lane >> 4;
    bf16x8 a0 = *(const bf16x8*)(As + swz_chunk(r, q));
    bf16x8 a1 = *(const bf16x8*)(As + swz_chunk(r, 4 + q));
    #pragma unroll
    for (int ct = 0; ct < 4; ++ct) {
      int br = ct * 16 + (lane & 15);
      bf16x8 b0 = *(const bf16x8*)(Bs + swz_chunk(br, q));
      bf16x8 b1 = *(const bf16x8*)(Bs + swz_chunk(br, 4 + q));
      acc[ct] = mfma16(a0, b0, acc[ct]);
      acc[ct] = mfma16(a1, b1, acc[ct]);
    }
  }
  #pragma unroll
  for (int ct = 0; ct < 4; ++ct) {
    int c = c0 + ct * 16 + (lane & 15);
    float bv = bias[c];
    int m = m0 + wv * 16 + (lane >> 4) * 4;
    int b_ = m >> 12, n = m & 4095;
    size_t off = ((size_t)(b_ * C + c)) * N + n;
    f32x4 xin = *(const f32x4*)(x + off);
    f32x4 res;
    #pragma unroll
    for (int j = 0; j < 4; ++j) res[j] = xin[j] + acc[ct][j] + bv;
    *(f32x4*)(out + off) = res;
  }
}

// ---------------------------------------------------------------------------
extern "C" void kernel_launch(void* const* d_in, const int* in_sizes, int n_in,
                              void* d_out, int out_size, void* d_ws, size_t ws_size,
                              hipStream_t stream) {
  const float* x     = (const float*)d_in[0];
  const float* gam   = (const float*)d_in[1];
  const float* bet   = (const float*)d_in[2];
  const float* wqkv  = (const float*)d_in[3];
  const float* bqkv  = (const float*)d_in[4];
  const float* wproj = (const float*)d_in[5];
  const float* bproj = (const float*)d_in[6];
  float* out = (float*)d_out;

  char* ws = (char*)d_ws;
  size_t off = 0;
  auto alloc = [&](size_t bytes) {
    void* p = ws + off;
    off += (bytes + 255) & ~(size_t)255;
    return p;
  };
  bf16_t* xn     = (bf16_t*)alloc((size_t)Bb * N * C * 2);
  bf16_t* wqkvT  = (bf16_t*)alloc((size_t)768 * 256 * 2);
  bf16_t* wprojT = (bf16_t*)alloc((size_t)256 * 256 * 2);
  bf16_t* Qb     = (bf16_t*)alloc((size_t)Bb * NH * N * HD * 2);
  bf16_t* Kb     = (bf16_t*)alloc((size_t)Bb * NH * N * HD * 2);
  bf16_t* Vtb    = (bf16_t*)alloc((size_t)Bb * NH * HD * N * 2);
  bf16_t* aout   = (bf16_t*)alloc((size_t)Bb * N * C * 2);
  if (ws_size < off) return;

  hipLaunchKernelGGL(ln_kernel, dim3(Bb * 64), dim3(256), 0, stream, x, gam, bet, xn);
  hipLaunchKernelGGL(conv_w, dim3(768), dim3(256), 0, stream, wqkv, wproj, wqkvT, wprojT);
  hipLaunchKernelGGL(gemm_qkv, dim3(128 * 6), dim3(256), 0, stream, xn, wqkvT, bqkv,
                     Qb, Kb, Vtb);
  hipLaunchKernelGGL(attn_kernel, dim3(16 * 32), dim3(512), 0, stream,
                     Qb, Kb, Vtb, aout);
  hipLaunchKernelGGL(gemm_proj, dim3(256 * 4), dim3(256), 0, stream, aout, wprojT,
                     bproj, x, out);
}

// Round 9
// 196.376 us; speedup vs baseline: 1.6591x; 1.0120x over previous
//
#include <hip/hip_runtime.h>
#include <hip/hip_bf16.h>

typedef __bf16 bf16_t;
typedef bf16_t bf16x8 __attribute__((ext_vector_type(8)));
typedef bf16_t bf16x4v __attribute__((ext_vector_type(4)));
typedef float f32x4 __attribute__((ext_vector_type(4)));
typedef float f32x16 __attribute__((ext_vector_type(16)));
typedef int i32x4 __attribute__((ext_vector_type(4)));
typedef int i32x2 __attribute__((ext_vector_type(2)));

constexpr int C = 256;
constexpr int Bb = 4;
constexpr int N = 4096;   // 64*64 tokens per batch
constexpr int NH = 4;
constexpr int HD = 64;
// fold (1/sqrt(C)) * log2(e) into Q so softmax uses exp2 directly
constexpr float SM_SCALE_LOG2E = 0.0625f * 1.44269504088896340736f;

// byte offset of 16B chunk `chunk` in row `row` of a [rows][64 bf16] LDS tile,
// XOR-swizzled (guide G4 / T2)
__device__ __forceinline__ int swz_chunk(int row, int chunk) {
  return row * 128 + ((chunk ^ (row & 7)) << 4);
}

__device__ __forceinline__ f32x4 mfma16(bf16x8 a, bf16x8 b, f32x4 c) {
  return __builtin_amdgcn_mfma_f32_16x16x32_bf16(a, b, c, 0, 0, 0);
}
__device__ __forceinline__ f32x16 mfma32(bf16x8 a, bf16x8 b, f32x16 c) {
  return __builtin_amdgcn_mfma_f32_32x32x16_bf16(a, b, c, 0, 0, 0);
}

// async global->LDS, 16B per lane; LDS dest = wave-uniform base + lane*16
__device__ __forceinline__ void glds16(const void* g, void* l) {
  __builtin_amdgcn_global_load_lds(
      (const __attribute__((address_space(1))) void*)g,
      (__attribute__((address_space(3))) void*)l, 16, 0, 0);
}

// pack two f32 into one dword of 2 bf16 (src0 -> low 16 bits)
__device__ __forceinline__ int cvt_pk_bf16(float lo, float hi) {
  int d;
  asm("v_cvt_pk_bf16_f32 %0, %1, %2" : "=v"(d) : "v"(lo), "v"(hi));
  return d;
}
// v_permlane32_swap_b32: r[0] = {X.lo | Y.lo}, r[1] = {X.hi | Y.hi}
__device__ __forceinline__ i32x2 plswap(int a, int b) {
  return __builtin_amdgcn_permlane32_swap(a, b, false, false);
}
__device__ __forceinline__ float xhalf_max(float v) {
  i32x2 r = plswap(__float_as_int(v), __float_as_int(v));
  return fmaxf(__int_as_float(r[0]), __int_as_float(r[1]));
}

// ---------------------------------------------------------------------------
// Kernel 1: LayerNorm over C with [B,C,N] -> [B,N,C] transpose, bf16 out
// 32 tokens/block, 512 blocks -> 4 blocks/CU (was 1).
// ---------------------------------------------------------------------------
__global__ __launch_bounds__(256, 4) void ln_kernel(
    const float* __restrict__ x, const float* __restrict__ gamma,
    const float* __restrict__ beta, bf16_t* __restrict__ xn) {
  __shared__ float tile[256][33];       // [channel][token], padded
  __shared__ float red[2][8][32];
  __shared__ float mu_s[32], rs_s[32];
  int tid = threadIdx.x;
  int b = blockIdx.x >> 7;
  int n0 = (blockIdx.x & 127) << 5;     // 32 tokens
  const float* xb = x + (size_t)b * C * N + n0;
  int tok = tid & 31, cg = tid >> 5;    // channel group 0..7
  #pragma unroll 8
  for (int i = 0; i < 32; ++i) {
    int c = cg * 32 + i;
    tile[c][tok] = xb[(size_t)c * N + tok];   // 2x128B segments per wave
  }
  __syncthreads();
  float s = 0.f, s2 = 0.f;
  #pragma unroll 8
  for (int i = 0; i < 32; ++i) {
    float v = tile[cg * 32 + i][tok];
    s += v; s2 += v * v;
  }
  red[0][cg][tok] = s; red[1][cg][tok] = s2;
  __syncthreads();
  if (tid < 32) {
    float ts = 0.f, ts2 = 0.f;
    #pragma unroll
    for (int g = 0; g < 8; ++g) { ts += red[0][g][tid]; ts2 += red[1][g][tid]; }
    float mu  = ts * (1.f / 256.f);
    float var = fmaxf(ts2 * (1.f / 256.f) - mu * mu, 0.f);
    mu_s[tid] = mu;
    rs_s[tid] = rsqrtf(var + 1e-5f);
  }
  __syncthreads();
  int ch = (tid & 63) * 4, tg = tid >> 6;
  f32x4 gm = *(const f32x4*)(gamma + ch);
  f32x4 bt = *(const f32x4*)(beta + ch);
  #pragma unroll
  for (int t = 0; t < 8; ++t) {
    int to = t * 4 + tg;
    float mu = mu_s[to], rs = rs_s[to];
    bf16x4v ov;
    #pragma unroll
    for (int j = 0; j < 4; ++j)
      ov[j] = (bf16_t)((tile[ch + j][to] - mu) * rs * gm[j] + bt[j]);
    *(bf16x4v*)(xn + ((size_t)(b * N + n0 + to)) * C + ch) = ov;  // 512B/wave
  }
}

// ---------------------------------------------------------------------------
// Kernel 2: weight transpose via 64x64 LDS tile — coalesced both sides
// ---------------------------------------------------------------------------
__global__ __launch_bounds__(256) void conv_w(
    const float* __restrict__ wqkv, const float* __restrict__ wproj,
    bf16_t* __restrict__ wqkvT, bf16_t* __restrict__ wprojT) {
  __shared__ float t[64][65];
  int blk = blockIdx.x, tid = threadIdx.x;
  const float* src; bf16_t* dst; int W, rt, ct;
  if (blk < 48) { src = wqkv; dst = wqkvT; W = 768; rt = blk / 12; ct = blk % 12; }
  else { int b2 = blk - 48; src = wproj; dst = wprojT; W = 256; rt = b2 >> 2; ct = b2 & 3; }
  int r0 = rt * 64, c0 = ct * 64;        // r = k-row, c = n-col
  int cc = tid & 63, r4 = tid >> 6;
  #pragma unroll
  for (int i = 0; i < 16; ++i) {
    int rr = i * 4 + r4;
    t[rr][cc] = src[(size_t)(r0 + rr) * W + c0 + cc];   // coalesced read
  }
  __syncthreads();
  #pragma unroll
  for (int i = 0; i < 16; ++i) {
    int nn = i * 4 + r4;
    dst[(size_t)(c0 + nn) * 256 + r0 + cc] = (bf16_t)t[cc][nn];  // coalesced write
  }
}

// ---------------------------------------------------------------------------
// Kernel 3: QKV GEMM, 128x128 tile — xn[16384,256] @ w[256,768] + b
// ---------------------------------------------------------------------------
__global__ __launch_bounds__(256, 2) void gemm_qkv(
    const bf16_t* __restrict__ xn, const bf16_t* __restrict__ wT,
    const float* __restrict__ bias,
    bf16_t* __restrict__ Q, bf16_t* __restrict__ K, bf16_t* __restrict__ Vt) {
  __shared__ char smem[32768];
  char* As = smem;            // [128 m][64 k] bf16 swizzled
  char* Bs = smem + 16384;    // [128 n][64 k]
  int tid = threadIdx.x, lane = tid & 63, wv = tid >> 6;
  int mt = blockIdx.x & 127, nt = blockIdx.x >> 7;   // 128 x 6
  int m0 = mt * 128, ncol0 = nt * 128;
  int wr = wv >> 1, wc = wv & 1;
  f32x4 acc[4][4];
  #pragma unroll
  for (int i = 0; i < 4; ++i)
    #pragma unroll
    for (int j = 0; j < 4; ++j) acc[i][j] = (f32x4){0.f, 0.f, 0.f, 0.f};
  int q = lane >> 4;
  for (int kt = 0; kt < 4; ++kt) {
    int k0 = kt * 64;
    __syncthreads();
    #pragma unroll
    for (int it = 0; it < 4; ++it) {
      int idx = it * 256 + tid, row = idx >> 3, cb = idx & 7;
      *(i32x4*)(As + swz_chunk(row, cb)) =
          *(const i32x4*)(xn + (size_t)(m0 + row) * C + k0 + cb * 8);
      *(i32x4*)(Bs + swz_chunk(row, cb)) =
          *(const i32x4*)(wT + (size_t)(ncol0 + row) * C + k0 + cb * 8);
    }
    __syncthreads();
    bf16x8 a[4][2];
    #pragma unroll
    for (int mi = 0; mi < 4; ++mi) {
      int ar = wr * 64 + mi * 16 + (lane & 15);
      a[mi][0] = *(const bf16x8*)(As + swz_chunk(ar, q));
      a[mi][1] = *(const bf16x8*)(As + swz_chunk(ar, 4 + q));
    }
    #pragma unroll
    for (int ci = 0; ci < 4; ++ci) {
      int br = wc * 64 + ci * 16 + (lane & 15);
      bf16x8 b0 = *(const bf16x8*)(Bs + swz_chunk(br, q));
      bf16x8 b1 = *(const bf16x8*)(Bs + swz_chunk(br, 4 + q));
      #pragma unroll
      for (int mi = 0; mi < 4; ++mi) {
        acc[mi][ci] = mfma16(a[mi][1], b1, mfma16(a[mi][0], b0, acc[mi][ci]));
      }
    }
  }
  #pragma unroll
  for (int ci = 0; ci < 4; ++ci) {
    int cg = ncol0 + wc * 64 + ci * 16 + (lane & 15);
    float bv = bias[cg];
    int sect = cg >> 8;          // 0=q, 1=k, 2=v
    int cc = cg & 255;
    int h = cc >> 6, d = cc & 63;
    #pragma unroll
    for (int mi = 0; mi < 4; ++mi) {
      #pragma unroll
      for (int j = 0; j < 4; ++j) {
        int m = m0 + wr * 64 + mi * 16 + (lane >> 4) * 4 + j;
        int b_ = m >> 12, n = m & 4095;
        float v = acc[mi][ci][j] + bv;
        if (sect == 0) {
          Q[((size_t)((b_ * NH + h) * N + n)) * HD + d] = (bf16_t)(v * SM_SCALE_LOG2E);
        } else if (sect == 1) {
          K[((size_t)((b_ * NH + h) * N + n)) * HD + d] = (bf16_t)v;
        } else {
          Vt[((size_t)((b_ * NH + h) * HD + d)) * N + n] = (bf16_t)v;
        }
      }
    }
  }
}

// ---------------------------------------------------------------------------
// Kernel 4: flash attention v6 — 32x32x16 MFMA, swapped operands,
// glds double-buffer staging, T12 P-in-registers, T13 defer-max,
// row-sum l via ones-MFMA (off the VALU pipe).
// ---------------------------------------------------------------------------
__global__ __launch_bounds__(512, 4) void attn_kernel(
    const bf16_t* __restrict__ Q, const bf16_t* __restrict__ K,
    const bf16_t* __restrict__ Vt, bf16_t* __restrict__ aout) {
  __shared__ char smem[67584];
  // [0,32K) buf0: K-even|V-even|K-odd|V-odd; [32K,64K) buf1; Q overlays buf1;
  // merge obuf overlays buf0; [64K,66K) m/l.
  int tid = threadIdx.x, lane = tid & 63, wv = tid >> 6;
  int hi = lane >> 5, qL = lane & 31;
  int wq = wv >> 1, par = wv & 1;
  int bh = blockIdx.x >> 5, qt = blockIdx.x & 31;
  int q0 = qt * 128;

  const bf16_t* Kbh = K + (size_t)bh * N * HD;
  const bf16_t* Vbh = Vt + (size_t)bh * HD * N;
  int sr = tid >> 3;                    // staging row 0..63
  int sc = (tid & 7) ^ (sr & 7);        // pre-swizzled source chunk (rule #21)

  {
    char* lb = smem;
    glds16(Kbh + (size_t)sr * HD + sc * 8,            lb + tid * 16);
    glds16(Vbh + (size_t)sr * N + sc * 8,             lb + 8192 + tid * 16);
    glds16(Kbh + (size_t)(64 + sr) * HD + sc * 8,     lb + 16384 + tid * 16);
    glds16(Vbh + (size_t)sr * N + 64 + sc * 8,        lb + 24576 + tid * 16);
  }
  char* Qt = smem + 32768;
  const bf16_t* Qbase = Q + ((size_t)bh * N + q0) * HD;
  #pragma unroll
  for (int it = 0; it < 2; ++it) {
    int idx = it * 512 + tid;
    int row = idx >> 3, cb = idx & 7;
    *(i32x4*)(Qt + swz_chunk(row, cb)) =
        *(const i32x4*)(Qbase + (size_t)row * HD + cb * 8);
  }
  __syncthreads();
  bf16x8 qb[4];
  #pragma unroll
  for (int hs = 0; hs < 4; ++hs)
    qb[hs] = *(const bf16x8*)(Qt + swz_chunk(wq * 32 + qL, hs * 2 + hi));

  bf16x8 onesf;
  #pragma unroll
  for (int i = 0; i < 8; ++i) onesf[i] = (bf16_t)1.0f;

  float m_r = -3.0e38f;
  f32x16 o0, o1, lacc;                  // lacc: l in every reg (ones-MFMA)
  #pragma unroll
  for (int i = 0; i < 16; ++i) { o0[i] = 0.f; o1[i] = 0.f; lacc[i] = 0.f; }

  for (int adv = 0; adv < 32; ++adv) {
    __syncthreads();                    // drains this adv's glds + prior reads
    if (adv < 31) {
      int n1 = (adv + 1) * 128;
      char* lb = smem + (((adv + 1) & 1) << 15);
      glds16(Kbh + (size_t)(n1 + sr) * HD + sc * 8,        lb + tid * 16);
      glds16(Vbh + (size_t)sr * N + n1 + sc * 8,           lb + 8192 + tid * 16);
      glds16(Kbh + (size_t)(n1 + 64 + sr) * HD + sc * 8,   lb + 16384 + tid * 16);
      glds16(Vbh + (size_t)sr * N + n1 + 64 + sc * 8,      lb + 24576 + tid * 16);
    }
    char* kbase = smem + ((adv & 1) << 15) + par * 16384;
    char* vbase = kbase + 8192;
    f32x16 s0, s1;
    #pragma unroll
    for (int i = 0; i < 16; ++i) { s0[i] = 0.f; s1[i] = 0.f; }
    #pragma unroll
    for (int hs = 0; hs < 4; ++hs) {
      bf16x8 ka0 = *(const bf16x8*)(kbase + swz_chunk(qL, hs * 2 + hi));
      bf16x8 ka1 = *(const bf16x8*)(kbase + swz_chunk(32 + qL, hs * 2 + hi));
      s0 = mfma32(ka0, qb[hs], s0);
      s1 = mfma32(ka1, qb[hs], s1);
    }
    // tile max: 3-ary (v_max3) tree over 32 lane-local values + pair exchange
    float t0 = fmaxf(fmaxf(s0[0], s0[1]), s0[2]);
    float t1 = fmaxf(fmaxf(s0[3], s0[4]), s0[5]);
    float t2 = fmaxf(fmaxf(s0[6], s0[7]), s0[8]);
    float t3 = fmaxf(fmaxf(s0[9], s0[10]), s0[11]);
    float t4 = fmaxf(fmaxf(s0[12], s0[13]), s0[14]);
    float t5 = fmaxf(fmaxf(s0[15], s1[0]), s1[1]);
    float t6 = fmaxf(fmaxf(s1[2], s1[3]), s1[4]);
    float t7 = fmaxf(fmaxf(s1[5], s1[6]), s1[7]);
    float t8 = fmaxf(fmaxf(s1[8], s1[9]), s1[10]);
    float t9 = fmaxf(fmaxf(s1[11], s1[12]), s1[13]);
    float ta = fmaxf(s1[14], s1[15]);
    float u0 = fmaxf(fmaxf(t0, t1), t2);
    float u1 = fmaxf(fmaxf(t3, t4), t5);
    float u2 = fmaxf(fmaxf(t6, t7), t8);
    float u3 = fmaxf(t9, ta);
    float tm = fmaxf(fmaxf(u0, u1), fmaxf(u2, u3));
    tm = xhalf_max(tm);
    // T13: rescale only when max grows by >8 (log2 domain)
    if (!__all(tm - m_r <= 8.f)) {
      float nm = fmaxf(m_r, tm);
      float f = __builtin_amdgcn_exp2f(m_r - nm);
      o0 *= f; o1 *= f; lacc *= f;
      m_r = nm;
    }
    #pragma unroll
    for (int i = 0; i < 16; ++i) s0[i] = __builtin_amdgcn_exp2f(s0[i] - m_r);
    #pragma unroll
    for (int i = 0; i < 16; ++i) s1[i] = __builtin_amdgcn_exp2f(s1[i] - m_r);
    // P-frags in registers (T12); row-sum l via ones-MFMA per slab
    #pragma unroll
    for (int t16 = 0; t16 < 4; ++t16) {
      int dE0, dE1, dO0, dO1;
      if (t16 < 2) {
        dE0 = cvt_pk_bf16(s0[t16 * 8 + 0], s0[t16 * 8 + 1]);
        dE1 = cvt_pk_bf16(s0[t16 * 8 + 2], s0[t16 * 8 + 3]);
        dO0 = cvt_pk_bf16(s0[t16 * 8 + 4], s0[t16 * 8 + 5]);
        dO1 = cvt_pk_bf16(s0[t16 * 8 + 6], s0[t16 * 8 + 7]);
      } else {
        dE0 = cvt_pk_bf16(s1[(t16 - 2) * 8 + 0], s1[(t16 - 2) * 8 + 1]);
        dE1 = cvt_pk_bf16(s1[(t16 - 2) * 8 + 2], s1[(t16 - 2) * 8 + 3]);
        dO0 = cvt_pk_bf16(s1[(t16 - 2) * 8 + 4], s1[(t16 - 2) * 8 + 5]);
        dO1 = cvt_pk_bf16(s1[(t16 - 2) * 8 + 6], s1[(t16 - 2) * 8 + 7]);
      }
      i32x2 rA = plswap(dE0, dO0);
      i32x2 rB = plswap(dE1, dO1);
      union { i32x4 i; bf16x8 h; } u;
      u.i = (i32x4){rA[0], rB[0], rA[1], rB[1]};
      bf16x8 va0 = *(const bf16x8*)(vbase + swz_chunk(qL, t16 * 2 + hi));
      bf16x8 va1 = *(const bf16x8*)(vbase + swz_chunk(32 + qL, t16 * 2 + hi));
      o0 = mfma32(va0, u.h, o0);
      o1 = mfma32(va1, u.h, o1);
      lacc = mfma32(onesf, u.h, lacc);  // D[q][*] = sum_k P[k][q], all regs equal
    }
  }
  float l_r = lacc[0];                  // full 64-token sum, both halves equal

  // ---- merge parity partners via LDS ----
  __syncthreads();
  float* mlb = (float*)(smem + 65536);   // [8 waves][32 q][2]
  if (hi == 0) {
    mlb[(wv * 32 + qL) * 2]     = m_r;
    mlb[(wv * 32 + qL) * 2 + 1] = l_r;
  }
  __syncthreads();
  float m_p = mlb[((wv ^ 1) * 32 + qL) * 2];
  float l_p = mlb[((wv ^ 1) * 32 + qL) * 2 + 1];
  float M = fmaxf(m_r, m_p);
  float w_s = __builtin_amdgcn_exp2f(m_r - M);
  float l_tot = l_r * w_s + l_p * __builtin_amdgcn_exp2f(m_p - M);
  char* obuf = smem + wq * 8192;
  if (par == 0) {
    #pragma unroll
    for (int g = 0; g < 8; ++g) {
      f32x4 t;
      #pragma unroll
      for (int j = 0; j < 4; ++j)
        t[j] = (g < 4 ? o0[g * 4 + j] : o1[(g - 4) * 4 + j]) * w_s;
      *(f32x4*)(obuf + swz_chunk(lane, g)) = t;
    }
  }
  __syncthreads();
  if (par == 1) {
    float inv = 1.f / l_tot;
    int qglob = q0 + wq * 32 + qL;
    int b_ = bh >> 2, h = bh & 3;
    bf16_t* ab = aout + ((size_t)b_ * N + qglob) * C + h * HD;
    #pragma unroll
    for (int g = 0; g < 8; ++g) {
      f32x4 part = *(const f32x4*)(obuf + swz_chunk(lane, g));
      int hdb = g >> 2, gg = g & 3;
      bf16x4v ov;
      #pragma unroll
      for (int j = 0; j < 4; ++j) {
        float own = hdb ? o1[gg * 4 + j] : o0[gg * 4 + j];
        ov[j] = (bf16_t)((part[j] + own * w_s) * inv);
      }
      *(bf16x4v*)(ab + hdb * 32 + gg * 8 + hi * 4) = ov;
    }
  }
}

// ---------------------------------------------------------------------------
// Kernel 5: proj GEMM 128x128 tile + bias + residual, fp32 float4 out
// ---------------------------------------------------------------------------
__global__ __launch_bounds__(256, 2) void gemm_proj(
    const bf16_t* __restrict__ aout, const bf16_t* __restrict__ wT,
    const float* __restrict__ bias, const float* __restrict__ x,
    float* __restrict__ out) {
  __shared__ char smem[32768];
  char* As = smem;
  char* Bs = smem + 16384;
  int tid = threadIdx.x, lane = tid & 63, wv = tid >> 6;
  int mt = blockIdx.x >> 1, nt = blockIdx.x & 1;   // 128 x 2
  int m0 = mt * 128, c0 = nt * 128;
  int wr = wv >> 1, wc = wv & 1;
  f32x4 acc[4][4];
  #pragma unroll
  for (int i = 0; i < 4; ++i)
    #pragma unroll
    for (int j = 0; j < 4; ++j) acc[i][j] = (f32x4){0.f, 0.f, 0.f, 0.f};
  int q = lane >> 4;
  for (int kt = 0; kt < 4; ++kt) {
    int k0 = kt * 64;
    __syncthreads();
    #pragma unroll
    for (int it = 0; it < 4; ++it) {
      int idx = it * 256 + tid, row = idx >> 3, cb = idx & 7;
      *(i32x4*)(As + swz_chunk(row, cb)) =
          *(const i32x4*)(aout + (size_t)(m0 + row) * C + k0 + cb * 8);
      *(i32x4*)(Bs + swz_chunk(row, cb)) =
          *(const i32x4*)(wT + (size_t)(c0 + row) * C + k0 + cb * 8);
    }
    __syncthreads();
    bf16x8 a[4][2];
    #pragma unroll
    for (int mi = 0; mi < 4; ++mi) {
      int ar = wr * 64 + mi * 16 + (lane & 15);
      a[mi][0] = *(const bf16x8*)(As + swz_chunk(ar, q));
      a[mi][1] = *(const bf16x8*)(As + swz_chunk(ar, 4 + q));
    }
    #pragma unroll
    for (int ci = 0; ci < 4; ++ci) {
      int br = wc * 64 + ci * 16 + (lane & 15);
      bf16x8 b0 = *(const bf16x8*)(Bs + swz_chunk(br, q));
      bf16x8 b1 = *(const bf16x8*)(Bs + swz_chunk(br, 4 + q));
      #pragma unroll
      for (int mi = 0; mi < 4; ++mi) {
        acc[mi][ci] = mfma16(a[mi][1], b1, mfma16(a[mi][0], b0, acc[mi][ci]));
      }
    }
  }
  #pragma unroll
  for (int ci = 0; ci < 4; ++ci) {
    int c = c0 + wc * 64 + ci * 16 + (lane & 15);
    float bv = bias[c];
    #pragma unroll
    for (int mi = 0; mi < 4; ++mi) {
      int m = m0 + wr * 64 + mi * 16 + (lane >> 4) * 4;
      int b_ = m >> 12, n = m & 4095;
      size_t off = ((size_t)(b_ * C + c)) * N + n;
      f32x4 xin = *(const f32x4*)(x + off);
      f32x4 res;
      #pragma unroll
      for (int j = 0; j < 4; ++j) res[j] = xin[j] + acc[mi][ci][j] + bv;
      *(f32x4*)(out + off) = res;
    }
  }
}

// ---------------------------------------------------------------------------
extern "C" void kernel_launch(void* const* d_in, const int* in_sizes, int n_in,
                              void* d_out, int out_size, void* d_ws, size_t ws_size,
                              hipStream_t stream) {
  const float* x     = (const float*)d_in[0];
  const float* gam   = (const float*)d_in[1];
  const float* bet   = (const float*)d_in[2];
  const float* wqkv  = (const float*)d_in[3];
  const float* bqkv  = (const float*)d_in[4];
  const float* wproj = (const float*)d_in[5];
  const float* bproj = (const float*)d_in[6];
  float* out = (float*)d_out;

  char* ws = (char*)d_ws;
  size_t off = 0;
  auto alloc = [&](size_t bytes) {
    void* p = ws + off;
    off += (bytes + 255) & ~(size_t)255;
    return p;
  };
  bf16_t* xn     = (bf16_t*)alloc((size_t)Bb * N * C * 2);
  bf16_t* wqkvT  = (bf16_t*)alloc((size_t)768 * 256 * 2);
  bf16_t* wprojT = (bf16_t*)alloc((size_t)256 * 256 * 2);
  bf16_t* Qb     = (bf16_t*)alloc((size_t)Bb * NH * N * HD * 2);
  bf16_t* Kb     = (bf16_t*)alloc((size_t)Bb * NH * N * HD * 2);
  bf16_t* Vtb    = (bf16_t*)alloc((size_t)Bb * NH * HD * N * 2);
  bf16_t* aout   = (bf16_t*)alloc((size_t)Bb * N * C * 2);
  if (ws_size < off) return;

  hipLaunchKernelGGL(ln_kernel, dim3(Bb * 128), dim3(256), 0, stream, x, gam, bet, xn);
  hipLaunchKernelGGL(conv_w, dim3(64), dim3(256), 0, stream, wqkv, wproj, wqkvT, wprojT);
  hipLaunchKernelGGL(gemm_qkv, dim3(128 * 6), dim3(256), 0, stream, xn, wqkvT, bqkv,
                     Qb, Kb, Vtb);
  hipLaunchKernelGGL(attn_kernel, dim3(16 * 32), dim3(512), 0, stream,
                     Qb, Kb, Vtb, aout);
  hipLaunchKernelGGL(gemm_proj, dim3(128 * 2), dim3(256), 0, stream, aout, wprojT,
                     bproj, x, out);
}

// Round 11
// 189.878 us; speedup vs baseline: 1.7159x; 1.0342x over previous
//
#include <hip/hip_runtime.h>
#include <hip/hip_bf16.h>

typedef __bf16 bf16_t;
typedef bf16_t bf16x8 __attribute__((ext_vector_type(8)));
typedef bf16_t bf16x4v __attribute__((ext_vector_type(4)));
typedef float f32x4 __attribute__((ext_vector_type(4)));
typedef float f32x16 __attribute__((ext_vector_type(16)));
typedef int i32x4 __attribute__((ext_vector_type(4)));
typedef int i32x2 __attribute__((ext_vector_type(2)));

constexpr int C = 256;
constexpr int Bb = 4;
constexpr int N = 4096;   // 64*64 tokens per batch
constexpr int NH = 4;
constexpr int HD = 64;
// fold (1/sqrt(C)) * log2(e) into Q so softmax uses exp2 directly
constexpr float SM_SCALE_LOG2E = 0.0625f * 1.44269504088896340736f;

// byte offset of 16B chunk `chunk` in row `row` of a [rows][64 bf16] LDS tile,
// XOR-swizzled (guide G4 / T2)
__device__ __forceinline__ int swz_chunk(int row, int chunk) {
  return row * 128 + ((chunk ^ (row & 7)) << 4);
}

__device__ __forceinline__ f32x4 mfma16(bf16x8 a, bf16x8 b, f32x4 c) {
  return __builtin_amdgcn_mfma_f32_16x16x32_bf16(a, b, c, 0, 0, 0);
}
__device__ __forceinline__ f32x16 mfma32(bf16x8 a, bf16x8 b, f32x16 c) {
  return __builtin_amdgcn_mfma_f32_32x32x16_bf16(a, b, c, 0, 0, 0);
}

// async global->LDS, 16B per lane; LDS dest = wave-uniform base + lane*16
__device__ __forceinline__ void glds16(const void* g, void* l) {
  __builtin_amdgcn_global_load_lds(
      (const __attribute__((address_space(1))) void*)g,
      (__attribute__((address_space(3))) void*)l, 16, 0, 0);
}

// pack two f32 into one dword of 2 bf16 (src0 -> low 16 bits)
__device__ __forceinline__ int cvt_pk_bf16(float lo, float hi) {
  int d;
  asm("v_cvt_pk_bf16_f32 %0, %1, %2" : "=v"(d) : "v"(lo), "v"(hi));
  return d;
}
// v_permlane32_swap_b32: r[0] = {X.lo | Y.lo}, r[1] = {X.hi | Y.hi}
__device__ __forceinline__ i32x2 plswap(int a, int b) {
  return __builtin_amdgcn_permlane32_swap(a, b, false, false);
}
__device__ __forceinline__ float xhalf_max(float v) {
  i32x2 r = plswap(__float_as_int(v), __float_as_int(v));
  return fmaxf(__int_as_float(r[0]), __int_as_float(r[1]));
}

// ---------------------------------------------------------------------------
// Kernel 1: LayerNorm over C with [B,C,N] -> [B,N,C] transpose, bf16 out
// ---------------------------------------------------------------------------
__global__ __launch_bounds__(256, 4) void ln_kernel(
    const float* __restrict__ x, const float* __restrict__ gamma,
    const float* __restrict__ beta, bf16_t* __restrict__ xn) {
  __shared__ float tile[256][33];       // [channel][token], padded
  __shared__ float red[2][8][32];
  __shared__ float mu_s[32], rs_s[32];
  int tid = threadIdx.x;
  int b = blockIdx.x >> 7;
  int n0 = (blockIdx.x & 127) << 5;     // 32 tokens
  const float* xb = x + (size_t)b * C * N + n0;
  int tok = tid & 31, cg = tid >> 5;    // channel group 0..7
  #pragma unroll 8
  for (int i = 0; i < 32; ++i) {
    int c = cg * 32 + i;
    tile[c][tok] = xb[(size_t)c * N + tok];
  }
  __syncthreads();
  float s = 0.f, s2 = 0.f;
  #pragma unroll 8
  for (int i = 0; i < 32; ++i) {
    float v = tile[cg * 32 + i][tok];
    s += v; s2 += v * v;
  }
  red[0][cg][tok] = s; red[1][cg][tok] = s2;
  __syncthreads();
  if (tid < 32) {
    float ts = 0.f, ts2 = 0.f;
    #pragma unroll
    for (int g = 0; g < 8; ++g) { ts += red[0][g][tid]; ts2 += red[1][g][tid]; }
    float mu  = ts * (1.f / 256.f);
    float var = fmaxf(ts2 * (1.f / 256.f) - mu * mu, 0.f);
    mu_s[tid] = mu;
    rs_s[tid] = rsqrtf(var + 1e-5f);
  }
  __syncthreads();
  int ch = (tid & 63) * 4, tg = tid >> 6;
  f32x4 gm = *(const f32x4*)(gamma + ch);
  f32x4 bt = *(const f32x4*)(beta + ch);
  #pragma unroll
  for (int t = 0; t < 8; ++t) {
    int to = t * 4 + tg;
    float mu = mu_s[to], rs = rs_s[to];
    bf16x4v ov;
    #pragma unroll
    for (int j = 0; j < 4; ++j)
      ov[j] = (bf16_t)((tile[ch + j][to] - mu) * rs * gm[j] + bt[j]);
    *(bf16x4v*)(xn + ((size_t)(b * N + n0 + to)) * C + ch) = ov;
  }
}

// ---------------------------------------------------------------------------
// Kernel 2: weight transpose via 64x64 LDS tile — coalesced both sides
// ---------------------------------------------------------------------------
__global__ __launch_bounds__(256) void conv_w(
    const float* __restrict__ wqkv, const float* __restrict__ wproj,
    bf16_t* __restrict__ wqkvT, bf16_t* __restrict__ wprojT) {
  __shared__ float t[64][65];
  int blk = blockIdx.x, tid = threadIdx.x;
  const float* src; bf16_t* dst; int W, rt, ct;
  if (blk < 48) { src = wqkv; dst = wqkvT; W = 768; rt = blk / 12; ct = blk % 12; }
  else { int b2 = blk - 48; src = wproj; dst = wprojT; W = 256; rt = b2 >> 2; ct = b2 & 3; }
  int r0 = rt * 64, c0 = ct * 64;
  int cc = tid & 63, r4 = tid >> 6;
  #pragma unroll
  for (int i = 0; i < 16; ++i) {
    int rr = i * 4 + r4;
    t[rr][cc] = src[(size_t)(r0 + rr) * W + c0 + cc];
  }
  __syncthreads();
  #pragma unroll
  for (int i = 0; i < 16; ++i) {
    int nn = i * 4 + r4;
    dst[(size_t)(c0 + nn) * 256 + r0 + cc] = (bf16_t)t[cc][nn];
  }
}

// ---------------------------------------------------------------------------
// Kernel 3: QKV GEMM, 128x128 tile. For V-blocks (nt>=4) the MFMA operand
// roles are SWAPPED (A<-wT rows=d, B<-xn rows=n) so the transposed-V store
// has lanes spanning n -> contiguous 32B runs instead of 8KB-stride scatter.
// ---------------------------------------------------------------------------
__global__ __launch_bounds__(256, 2) void gemm_qkv(
    const bf16_t* __restrict__ xn, const bf16_t* __restrict__ wT,
    const float* __restrict__ bias,
    bf16_t* __restrict__ Q, bf16_t* __restrict__ K, bf16_t* __restrict__ Vt) {
  __shared__ char smem[32768];
  char* As = smem;            // [128 m][64 k] bf16 swizzled
  char* Bs = smem + 16384;    // [128 n][64 k]
  int tid = threadIdx.x, lane = tid & 63, wv = tid >> 6;
  int mt = blockIdx.x & 127, nt = blockIdx.x >> 7;   // 128 x 6
  int m0 = mt * 128, ncol0 = nt * 128;
  bool vsec = (nt >= 4);
  char* Arows = vsec ? Bs : As;   // rows = output rows
  char* Brows = vsec ? As : Bs;   // rows = output cols
  int wr = wv >> 1, wc = wv & 1;
  f32x4 acc[4][4];
  #pragma unroll
  for (int i = 0; i < 4; ++i)
    #pragma unroll
    for (int j = 0; j < 4; ++j) acc[i][j] = (f32x4){0.f, 0.f, 0.f, 0.f};
  int q = lane >> 4;
  for (int kt = 0; kt < 4; ++kt) {
    int k0 = kt * 64;
    __syncthreads();
    #pragma unroll
    for (int it = 0; it < 4; ++it) {
      int idx = it * 256 + tid, row = idx >> 3, cb = idx & 7;
      *(i32x4*)(As + swz_chunk(row, cb)) =
          *(const i32x4*)(xn + (size_t)(m0 + row) * C + k0 + cb * 8);
      *(i32x4*)(Bs + swz_chunk(row, cb)) =
          *(const i32x4*)(wT + (size_t)(ncol0 + row) * C + k0 + cb * 8);
    }
    __syncthreads();
    bf16x8 a[4][2];
    #pragma unroll
    for (int mi = 0; mi < 4; ++mi) {
      int ar = wr * 64 + mi * 16 + (lane & 15);
      a[mi][0] = *(const bf16x8*)(Arows + swz_chunk(ar, q));
      a[mi][1] = *(const bf16x8*)(Arows + swz_chunk(ar, 4 + q));
    }
    #pragma unroll
    for (int ci = 0; ci < 4; ++ci) {
      int br = wc * 64 + ci * 16 + (lane & 15);
      bf16x8 b0 = *(const bf16x8*)(Brows + swz_chunk(br, q));
      bf16x8 b1 = *(const bf16x8*)(Brows + swz_chunk(br, 4 + q));
      #pragma unroll
      for (int mi = 0; mi < 4; ++mi) {
        acc[mi][ci] = mfma16(a[mi][1], b1, mfma16(a[mi][0], b0, acc[mi][ci]));
      }
    }
  }
  if (!vsec) {
    // rows = tokens m, cols = ncol (Q or K section)
    #pragma unroll
    for (int ci = 0; ci < 4; ++ci) {
      int cg = ncol0 + wc * 64 + ci * 16 + (lane & 15);
      float bv = bias[cg];
      int sect = cg >> 8;        // 0=q, 1=k
      int cc = cg & 255;
      int h = cc >> 6, d = cc & 63;
      #pragma unroll
      for (int mi = 0; mi < 4; ++mi) {
        #pragma unroll
        for (int j = 0; j < 4; ++j) {
          int m = m0 + wr * 64 + mi * 16 + (lane >> 4) * 4 + j;
          int b_ = m >> 12, n = m & 4095;
          float v = acc[mi][ci][j] + bv;
          if (sect == 0) {
            Q[((size_t)((b_ * NH + h) * N + n)) * HD + d] =
                (bf16_t)(v * SM_SCALE_LOG2E);
          } else {
            K[((size_t)((b_ * NH + h) * N + n)) * HD + d] = (bf16_t)v;
          }
        }
      }
    }
  } else {
    // rows = ncol (V channels), cols = tokens n -> lanes span n (coalesced)
    #pragma unroll
    for (int mi = 0; mi < 4; ++mi) {
      #pragma unroll
      for (int j = 0; j < 4; ++j) {
        int cg = ncol0 + wr * 64 + mi * 16 + (lane >> 4) * 4 + j;  // 512..767
        float bv = bias[cg];
        int cc = cg & 255;
        int h = cc >> 6, d = cc & 63;
        #pragma unroll
        for (int ci = 0; ci < 4; ++ci) {
          int ng = m0 + wc * 64 + ci * 16 + (lane & 15);
          int b_ = ng >> 12, n = ng & 4095;
          Vt[((size_t)((b_ * NH + h) * HD + d)) * N + n] =
              (bf16_t)(acc[mi][ci][j] + bv);
        }
      }
    }
  }
}

// ---------------------------------------------------------------------------
// Kernel 4: flash attention v6 — unchanged from R9 (control)
// ---------------------------------------------------------------------------
__global__ __launch_bounds__(512, 4) void attn_kernel(
    const bf16_t* __restrict__ Q, const bf16_t* __restrict__ K,
    const bf16_t* __restrict__ Vt, bf16_t* __restrict__ aout) {
  __shared__ char smem[67584];
  int tid = threadIdx.x, lane = tid & 63, wv = tid >> 6;
  int hi = lane >> 5, qL = lane & 31;
  int wq = wv >> 1, par = wv & 1;
  int bh = blockIdx.x >> 5, qt = blockIdx.x & 31;
  int q0 = qt * 128;

  const bf16_t* Kbh = K + (size_t)bh * N * HD;
  const bf16_t* Vbh = Vt + (size_t)bh * HD * N;
  int sr = tid >> 3;
  int sc = (tid & 7) ^ (sr & 7);

  {
    char* lb = smem;
    glds16(Kbh + (size_t)sr * HD + sc * 8,            lb + tid * 16);
    glds16(Vbh + (size_t)sr * N + sc * 8,             lb + 8192 + tid * 16);
    glds16(Kbh + (size_t)(64 + sr) * HD + sc * 8,     lb + 16384 + tid * 16);
    glds16(Vbh + (size_t)sr * N + 64 + sc * 8,        lb + 24576 + tid * 16);
  }
  char* Qt = smem + 32768;
  const bf16_t* Qbase = Q + ((size_t)bh * N + q0) * HD;
  #pragma unroll
  for (int it = 0; it < 2; ++it) {
    int idx = it * 512 + tid;
    int row = idx >> 3, cb = idx & 7;
    *(i32x4*)(Qt + swz_chunk(row, cb)) =
        *(const i32x4*)(Qbase + (size_t)row * HD + cb * 8);
  }
  __syncthreads();
  bf16x8 qb[4];
  #pragma unroll
  for (int hs = 0; hs < 4; ++hs)
    qb[hs] = *(const bf16x8*)(Qt + swz_chunk(wq * 32 + qL, hs * 2 + hi));

  bf16x8 onesf;
  #pragma unroll
  for (int i = 0; i < 8; ++i) onesf[i] = (bf16_t)1.0f;

  float m_r = -3.0e38f;
  f32x16 o0, o1, lacc;
  #pragma unroll
  for (int i = 0; i < 16; ++i) { o0[i] = 0.f; o1[i] = 0.f; lacc[i] = 0.f; }

  for (int adv = 0; adv < 32; ++adv) {
    __syncthreads();
    if (adv < 31) {
      int n1 = (adv + 1) * 128;
      char* lb = smem + (((adv + 1) & 1) << 15);
      glds16(Kbh + (size_t)(n1 + sr) * HD + sc * 8,        lb + tid * 16);
      glds16(Vbh + (size_t)sr * N + n1 + sc * 8,           lb + 8192 + tid * 16);
      glds16(Kbh + (size_t)(n1 + 64 + sr) * HD + sc * 8,   lb + 16384 + tid * 16);
      glds16(Vbh + (size_t)sr * N + n1 + 64 + sc * 8,      lb + 24576 + tid * 16);
    }
    char* kbase = smem + ((adv & 1) << 15) + par * 16384;
    char* vbase = kbase + 8192;
    f32x16 s0, s1;
    #pragma unroll
    for (int i = 0; i < 16; ++i) { s0[i] = 0.f; s1[i] = 0.f; }
    #pragma unroll
    for (int hs = 0; hs < 4; ++hs) {
      bf16x8 ka0 = *(const bf16x8*)(kbase + swz_chunk(qL, hs * 2 + hi));
      bf16x8 ka1 = *(const bf16x8*)(kbase + swz_chunk(32 + qL, hs * 2 + hi));
      s0 = mfma32(ka0, qb[hs], s0);
      s1 = mfma32(ka1, qb[hs], s1);
    }
    float t0 = fmaxf(fmaxf(s0[0], s0[1]), s0[2]);
    float t1 = fmaxf(fmaxf(s0[3], s0[4]), s0[5]);
    float t2 = fmaxf(fmaxf(s0[6], s0[7]), s0[8]);
    float t3 = fmaxf(fmaxf(s0[9], s0[10]), s0[11]);
    float t4 = fmaxf(fmaxf(s0[12], s0[13]), s0[14]);
    float t5 = fmaxf(fmaxf(s0[15], s1[0]), s1[1]);
    float t6 = fmaxf(fmaxf(s1[2], s1[3]), s1[4]);
    float t7 = fmaxf(fmaxf(s1[5], s1[6]), s1[7]);
    float t8 = fmaxf(fmaxf(s1[8], s1[9]), s1[10]);
    float t9 = fmaxf(fmaxf(s1[11], s1[12]), s1[13]);
    float ta = fmaxf(s1[14], s1[15]);
    float u0 = fmaxf(fmaxf(t0, t1), t2);
    float u1 = fmaxf(fmaxf(t3, t4), t5);
    float u2 = fmaxf(fmaxf(t6, t7), t8);
    float u3 = fmaxf(t9, ta);
    float tm = fmaxf(fmaxf(u0, u1), fmaxf(u2, u3));
    tm = xhalf_max(tm);
    if (!__all(tm - m_r <= 8.f)) {
      float nm = fmaxf(m_r, tm);
      float f = __builtin_amdgcn_exp2f(m_r - nm);
      o0 *= f; o1 *= f; lacc *= f;
      m_r = nm;
    }
    #pragma unroll
    for (int i = 0; i < 16; ++i) s0[i] = __builtin_amdgcn_exp2f(s0[i] - m_r);
    #pragma unroll
    for (int i = 0; i < 16; ++i) s1[i] = __builtin_amdgcn_exp2f(s1[i] - m_r);
    #pragma unroll
    for (int t16 = 0; t16 < 4; ++t16) {
      int dE0, dE1, dO0, dO1;
      if (t16 < 2) {
        dE0 = cvt_pk_bf16(s0[t16 * 8 + 0], s0[t16 * 8 + 1]);
        dE1 = cvt_pk_bf16(s0[t16 * 8 + 2], s0[t16 * 8 + 3]);
        dO0 = cvt_pk_bf16(s0[t16 * 8 + 4], s0[t16 * 8 + 5]);
        dO1 = cvt_pk_bf16(s0[t16 * 8 + 6], s0[t16 * 8 + 7]);
      } else {
        dE0 = cvt_pk_bf16(s1[(t16 - 2) * 8 + 0], s1[(t16 - 2) * 8 + 1]);
        dE1 = cvt_pk_bf16(s1[(t16 - 2) * 8 + 2], s1[(t16 - 2) * 8 + 3]);
        dO0 = cvt_pk_bf16(s1[(t16 - 2) * 8 + 4], s1[(t16 - 2) * 8 + 5]);
        dO1 = cvt_pk_bf16(s1[(t16 - 2) * 8 + 6], s1[(t16 - 2) * 8 + 7]);
      }
      i32x2 rA = plswap(dE0, dO0);
      i32x2 rB = plswap(dE1, dO1);
      union { i32x4 i; bf16x8 h; } u;
      u.i = (i32x4){rA[0], rB[0], rA[1], rB[1]};
      bf16x8 va0 = *(const bf16x8*)(vbase + swz_chunk(qL, t16 * 2 + hi));
      bf16x8 va1 = *(const bf16x8*)(vbase + swz_chunk(32 + qL, t16 * 2 + hi));
      o0 = mfma32(va0, u.h, o0);
      o1 = mfma32(va1, u.h, o1);
      lacc = mfma32(onesf, u.h, lacc);
    }
  }
  float l_r = lacc[0];

  __syncthreads();
  float* mlb = (float*)(smem + 65536);
  if (hi == 0) {
    mlb[(wv * 32 + qL) * 2]     = m_r;
    mlb[(wv * 32 + qL) * 2 + 1] = l_r;
  }
  __syncthreads();
  float m_p = mlb[((wv ^ 1) * 32 + qL) * 2];
  float l_p = mlb[((wv ^ 1) * 32 + qL) * 2 + 1];
  float M = fmaxf(m_r, m_p);
  float w_s = __builtin_amdgcn_exp2f(m_r - M);
  float l_tot = l_r * w_s + l_p * __builtin_amdgcn_exp2f(m_p - M);
  char* obuf = smem + wq * 8192;
  if (par == 0) {
    #pragma unroll
    for (int g = 0; g < 8; ++g) {
      f32x4 t;
      #pragma unroll
      for (int j = 0; j < 4; ++j)
        t[j] = (g < 4 ? o0[g * 4 + j] : o1[(g - 4) * 4 + j]) * w_s;
      *(f32x4*)(obuf + swz_chunk(lane, g)) = t;
    }
  }
  __syncthreads();
  if (par == 1) {
    float inv = 1.f / l_tot;
    int qglob = q0 + wq * 32 + qL;
    int b_ = bh >> 2, h = bh & 3;
    bf16_t* ab = aout + ((size_t)b_ * N + qglob) * C + h * HD;
    #pragma unroll
    for (int g = 0; g < 8; ++g) {
      f32x4 part = *(const f32x4*)(obuf + swz_chunk(lane, g));
      int hdb = g >> 2, gg = g & 3;
      bf16x4v ov;
      #pragma unroll
      for (int j = 0; j < 4; ++j) {
        float own = hdb ? o1[gg * 4 + j] : o0[gg * 4 + j];
        ov[j] = (bf16_t)((part[j] + own * w_s) * inv);
      }
      *(bf16x4v*)(ab + hdb * 32 + gg * 8 + hi * 4) = ov;
    }
  }
}

// ---------------------------------------------------------------------------
// Kernel 5: proj GEMM 128x128 tile, OPERAND-SWAPPED (A<-wT rows=c,
// B<-aout rows=n) so out/x accesses are 64B-coalesced along n.
// ---------------------------------------------------------------------------
__global__ __launch_bounds__(256, 2) void gemm_proj(
    const bf16_t* __restrict__ aout, const bf16_t* __restrict__ wT,
    const float* __restrict__ bias, const float* __restrict__ x,
    float* __restrict__ out) {
  __shared__ char smem[32768];
  char* As = smem;            // [128 n][64 k] (aout rows)
  char* Bs = smem + 16384;    // [128 c][64 k] (wT rows)
  int tid = threadIdx.x, lane = tid & 63, wv = tid >> 6;
  int mt = blockIdx.x >> 1, nt = blockIdx.x & 1;   // 128 x 2
  int m0 = mt * 128, c0 = nt * 128;
  int wr = wv >> 1, wc = wv & 1;
  f32x4 acc[4][4];
  #pragma unroll
  for (int i = 0; i < 4; ++i)
    #pragma unroll
    for (int j = 0; j < 4; ++j) acc[i][j] = (f32x4){0.f, 0.f, 0.f, 0.f};
  int q = lane >> 4;
  for (int kt = 0; kt < 4; ++kt) {
    int k0 = kt * 64;
    __syncthreads();
    #pragma unroll
    for (int it = 0; it < 4; ++it) {
      int idx = it * 256 + tid, row = idx >> 3, cb = idx & 7;
      *(i32x4*)(As + swz_chunk(row, cb)) =
          *(const i32x4*)(aout + (size_t)(m0 + row) * C + k0 + cb * 8);
      *(i32x4*)(Bs + swz_chunk(row, cb)) =
          *(const i32x4*)(wT + (size_t)(c0 + row) * C + k0 + cb * 8);
    }
    __syncthreads();
    bf16x8 a[4][2];   // A-frags from wT rows (c)
    #pragma unroll
    for (int mi = 0; mi < 4; ++mi) {
      int ar = wr * 64 + mi * 16 + (lane & 15);
      a[mi][0] = *(const bf16x8*)(Bs + swz_chunk(ar, q));
      a[mi][1] = *(const bf16x8*)(Bs + swz_chunk(ar, 4 + q));
    }
    #pragma unroll
    for (int ci = 0; ci < 4; ++ci) {
      int br = wc * 64 + ci * 16 + (lane & 15);
      bf16x8 b0 = *(const bf16x8*)(As + swz_chunk(br, q));
      bf16x8 b1 = *(const bf16x8*)(As + swz_chunk(br, 4 + q));
      #pragma unroll
      for (int mi = 0; mi < 4; ++mi) {
        acc[mi][ci] = mfma16(a[mi][1], b1, mfma16(a[mi][0], b0, acc[mi][ci]));
      }
    }
  }
  // rows = c, cols = n -> lanes span n: scalar fp32, 64B per 16-lane group
  #pragma unroll
  for (int mi = 0; mi < 4; ++mi) {
    #pragma unroll
    for (int j = 0; j < 4; ++j) {
      int c = c0 + wr * 64 + mi * 16 + (lane >> 4) * 4 + j;
      float bv = bias[c];
      #pragma unroll
      for (int ci = 0; ci < 4; ++ci) {
        int ng = m0 + wc * 64 + ci * 16 + (lane & 15);
        int b_ = ng >> 12, n = ng & 4095;
        size_t off = ((size_t)(b_ * C + c)) * N + n;
        out[off] = x[off] + acc[mi][ci][j] + bv;
      }
    }
  }
}

// ---------------------------------------------------------------------------
extern "C" void kernel_launch(void* const* d_in, const int* in_sizes, int n_in,
                              void* d_out, int out_size, void* d_ws, size_t ws_size,
                              hipStream_t stream) {
  const float* x     = (const float*)d_in[0];
  const float* gam   = (const float*)d_in[1];
  const float* bet   = (const float*)d_in[2];
  const float* wqkv  = (const float*)d_in[3];
  const float* bqkv  = (const float*)d_in[4];
  const float* wproj = (const float*)d_in[5];
  const float* bproj = (const float*)d_in[6];
  float* out = (float*)d_out;

  char* ws = (char*)d_ws;
  size_t off = 0;
  auto alloc = [&](size_t bytes) {
    void* p = ws + off;
    off += (bytes + 255) & ~(size_t)255;
    return p;
  };
  bf16_t* xn     = (bf16_t*)alloc((size_t)Bb * N * C * 2);
  bf16_t* wqkvT  = (bf16_t*)alloc((size_t)768 * 256 * 2);
  bf16_t* wprojT = (bf16_t*)alloc((size_t)256 * 256 * 2);
  bf16_t* Qb     = (bf16_t*)alloc((size_t)Bb * NH * N * HD * 2);
  bf16_t* Kb     = (bf16_t*)alloc((size_t)Bb * NH * N * HD * 2);
  bf16_t* Vtb    = (bf16_t*)alloc((size_t)Bb * NH * HD * N * 2);
  bf16_t* aout   = (bf16_t*)alloc((size_t)Bb * N * C * 2);
  if (ws_size < off) return;

  hipLaunchKernelGGL(ln_kernel, dim3(Bb * 128), dim3(256), 0, stream, x, gam, bet, xn);
  hipLaunchKernelGGL(conv_w, dim3(64), dim3(256), 0, stream, wqkv, wproj, wqkvT, wprojT);
  hipLaunchKernelGGL(gemm_qkv, dim3(128 * 6), dim3(256), 0, stream, xn, wqkvT, bqkv,
                     Qb, Kb, Vtb);
  hipLaunchKernelGGL(attn_kernel, dim3(16 * 32), dim3(512), 0, stream,
                     Qb, Kb, Vtb, aout);
  hipLaunchKernelGGL(gemm_proj, dim3(128 * 2), dim3(256), 0, stream, aout, wprojT,
                     bproj, x, out);
}